// Round 7
// baseline (414.600 us; speedup 1.0000x reference)
//
#include <hip/hip_runtime.h>
#include <math.h>

#define NE 65536
#define NN 8192
#define NT16 80      // node-tiles of 16 per z (80*16=1280 >> max z-group size ~900)
#define ECAP2 192    // max edges per 16-node block (mean 128, sd ~11; fixed input, 5.7 sigma)

typedef unsigned short u16;
typedef float f32x4 __attribute__((ext_vector_type(4)));
typedef __bf16 bf16x8 __attribute__((ext_vector_type(8)));
typedef unsigned short u16x8 __attribute__((ext_vector_type(8)));

// ---- ws layout (bytes); total 141,394,072 (proven safe R1-R6) ----
#define WS_R1       0u           // 134,217,728: A[e][512] f32 (k_edge -> k_back)
#define WS_X        134217728u   // 4,194,304
#define WS_CH       138412032u   // 1,310,720  CH[lz=40][kc=16][u'=128][j=8] u16
#define WS_CL       139722752u   // 1,310,720
#define WS_COUNTS   141033472u   // 32,768 (counts; becomes cursor after k_scan)
#define WS_ZCNT     141066240u   // 64
#define WS_ROWSTART 141066304u   // 32,772
#define WS_ZRS      141099076u   // 44 (11 ints)
#define WS_ZCUR     141099120u   // 40
#define WS_ELIST    141099160u   // 262,144
#define WS_ZNODES   141361304u   // 32,768 -> end 141,394,072

// ---- d_out scratch for k_prep weights (k_prep -> k_edge; overwritten by k_back's out) ----
// f32: W1T[64][8] @0, W2T[64][64] @512, W3T[64][64] @4608 (float idx)
// u16: W4Th @byte 34816, W4Tl @byte 100352 -> end 165,888 B << 64MB

__device__ __forceinline__ unsigned bf16_rne(float v) {
    unsigned u = __float_as_uint(v);
    return (u + 0x7FFFu + ((u >> 16) & 1u)) >> 16;
}

// ---------------- CSR build (edge by dst) + z-grouping of nodes ----------------
__global__ void k_count(const int* __restrict__ eidx, const float* __restrict__ na,
                        int* __restrict__ counts, int* __restrict__ zcnt) {
    int e = blockIdx.x * 256 + threadIdx.x;
    if (e < NE) atomicAdd(&counts[eidx[NE + e]], 1);
    if (e < NN) {
        const float* row = na + (size_t)e * 10;
        int z = 0;
        #pragma unroll
        for (int w = 1; w < 10; ++w) if (row[w] > 0.5f) z = w;
        atomicAdd(&zcnt[z], 1);
    }
}

__global__ __launch_bounds__(1024) void k_scan(int* __restrict__ counts,  // also becomes cursor
                                               int* __restrict__ row_start,
                                               const int* __restrict__ zcnt,
                                               int* __restrict__ zrs, int* __restrict__ zcur) {
    __shared__ int sd[1024];
    int t = threadIdx.x;
    int c[8];
    int s = 0;
    #pragma unroll
    for (int i = 0; i < 8; ++i) { c[i] = counts[t * 8 + i]; s += c[i]; }
    sd[t] = s;
    __syncthreads();
    for (int off = 1; off < 1024; off <<= 1) {
        int v = (t >= off) ? sd[t - off] : 0;
        __syncthreads();
        sd[t] += v;
        __syncthreads();
    }
    int run = (t == 0) ? 0 : sd[t - 1];
    #pragma unroll
    for (int i = 0; i < 8; ++i) {
        row_start[t * 8 + i] = run;
        counts[t * 8 + i] = run;   // cursor
        run += c[i];
    }
    if (t == 1023) row_start[8192] = run;
    if (t == 0) {
        int zr = 0;
        for (int i = 0; i < 10; ++i) { zrs[i] = zr; zcur[i] = zr; zr += zcnt[i]; }
        zrs[10] = zr;
    }
}

__global__ void k_scatter(const int* __restrict__ eidx, const float* __restrict__ na,
                          int* __restrict__ cursor, int* __restrict__ elist,
                          int* __restrict__ zcur, int* __restrict__ znodes) {
    int e = blockIdx.x * 256 + threadIdx.x;
    if (e < NE) {
        int p = atomicAdd(&cursor[eidx[NE + e]], 1);
        elist[p] = e;
    }
    if (e < NN) {
        const float* row = na + (size_t)e * 10;
        int z = 0;
        #pragma unroll
        for (int w = 1; w < 10; ++w) if (row[w] > 0.5f) z = w;
        int p = atomicAdd(&zcur[z], 1);
        znodes[p] = e;
    }
}

// ---------------- weight prep -> d_out scratch ----------------
__global__ __launch_bounds__(256) void k_prep(const float* __restrict__ W1, const float* __restrict__ W2,
                                              const float* __restrict__ W3, const float* __restrict__ W4,
                                              float* __restrict__ W1T, float* __restrict__ W2T,
                                              float* __restrict__ W3T, u16* __restrict__ W4Th,
                                              u16* __restrict__ W4Tl) {
    int t = blockIdx.x * 256 + threadIdx.x;
    if (t < 512) { int c = t >> 3, k = t & 7; W1T[t] = W1[k * 64 + c]; }
    if (t < 4096) {
        int c = t >> 6, k = t & 63;
        W2T[t] = W2[k * 64 + c];
        W3T[t] = W3[k * 64 + c];
    }
    if (t < 32768) {
        int c = t >> 6, k = t & 63;
        float v = W4[k * 512 + c];
        unsigned h = bf16_rne(v);
        float fh = __uint_as_float(h << 16);
        unsigned lo = bf16_rne(v - fh);
        W4Th[t] = (u16)h;
        W4Tl[t] = (u16)lo;
    }
}

// ---------------- x = node_feats @ W_up / sqrt(128) ----------------
__global__ __launch_bounds__(256) void k_x(const float* __restrict__ nf,
                                           const float* __restrict__ Wup,
                                           float* __restrict__ x) {
    __shared__ float nf_s[16][128];
    int n0 = blockIdx.x * 16;
    int t = threadIdx.x;
    for (int i = t; i < 16 * 128; i += 256) nf_s[i >> 7][i & 127] = nf[n0 * 128 + i];
    __syncthreads();
    int mc = t & 127, half = t >> 7;
    float acc[8];
    #pragma unroll
    for (int j = 0; j < 8; ++j) acc[j] = 0.f;
    for (int k = 0; k < 128; ++k) {
        float w = Wup[k * 128 + mc];
        #pragma unroll
        for (int j = 0; j < 8; ++j) acc[j] += nf_s[half * 8 + j][k] * w;
    }
    const float rs = 0.08838834764831845f;  // 1/sqrt(128)
    #pragma unroll
    for (int j = 0; j < 8; ++j) x[(n0 + half * 8 + j) * 128 + mc] = acc[j] * rs;
}

// ---------------- C precompute -> split-bf16 in MFMA A-frag layout ----------------
__global__ __launch_bounds__(256) void k_C(const float* __restrict__ Wlin,
                                           const float* __restrict__ Wskip,
                                           u16* __restrict__ CH, u16* __restrict__ CL) {
    __shared__ float wl_s[16][128];
    int b = blockIdx.x;
    int lz = b >> 3, ut = b & 7;
    int l = lz / 10, z = lz % 10;
    int t = threadIdx.x;
    for (int i = t; i < 16 * 128; i += 256) {
        int u = i >> 7, v = i & 127;
        wl_s[u][v] = Wlin[(l * 128 + ut * 16 + u) * 128 + v];
    }
    __syncthreads();
    int u2 = t & 127, uh = t >> 7;
    float acc[8];
    #pragma unroll
    for (int r = 0; r < 8; ++r) acc[r] = 0.f;
    const float* Wsk = Wskip + ((size_t)l * 128 * 10 + z) * 128 + u2;  // stride over v: 1280
    for (int v = 0; v < 128; v += 4) {
        float s0 = Wsk[(size_t)(v + 0) * 1280];
        float s1 = Wsk[(size_t)(v + 1) * 1280];
        float s2 = Wsk[(size_t)(v + 2) * 1280];
        float s3 = Wsk[(size_t)(v + 3) * 1280];
        #pragma unroll
        for (int r = 0; r < 8; ++r) {
            int u = uh * 8 + r;
            acc[r] += wl_s[u][v] * s0 + wl_s[u][v + 1] * s1
                    + wl_s[u][v + 2] * s2 + wl_s[u][v + 3] * s3;
        }
    }
    const float scale = 3.0881618e-04f;  // (1/sqrt(128)/8) * (1/sqrt(1280))
    int kc = ut * 2 + uh;
    u16x8 vh, vl;
    #pragma unroll
    for (int r = 0; r < 8; ++r) {
        float v = acc[r] * scale;
        unsigned h = bf16_rne(v);
        float fh = __uint_as_float(h << 16);
        unsigned lo = bf16_rne(v - fh);
        vh[r] = (u16)h;
        vl[r] = (u16)lo;
    }
    size_t off = ((size_t)(lz * 16 + kc) * 128 + u2) * 8;
    *(u16x8*)(CH + off) = vh;
    *(u16x8*)(CL + off) = vl;
}

// ---------------- edge MLP (weights-in-VGPR) + W4 GEMM (split-bf16 MFMA) -> A (R5, 124us) ----------------
__global__ __launch_bounds__(256) void k_edge(const float* __restrict__ ef,
                                              const int* __restrict__ eidx,
                                              const float* __restrict__ b1, const float* __restrict__ b2,
                                              const float* __restrict__ b3, const float* __restrict__ b4,
                                              const float* __restrict__ W1T, const float* __restrict__ W2T,
                                              const float* __restrict__ W3T,
                                              const u16* __restrict__ W4Th, const u16* __restrict__ W4Tl,
                                              const float* __restrict__ x,
                                              float* __restrict__ A) {
    __shared__ float ef_s[32][8];
    __shared__ float ha[32][64];
    __shared__ float hb[32][64];
    __shared__ u16 HFh[32 * 72];
    __shared__ u16 HFl[32 * 72];
    __shared__ int srcs[32];
    int t = threadIdx.x;
    int e0 = blockIdx.x * 32;
    ef_s[t >> 3][t & 7] = ef[e0 * 8 + t];
    if (t < 32) srcs[t] = eidx[e0 + t];
    __syncthreads();
    int col = t & 63, wv = t >> 6;
    {
        float4 w1a = *(const float4*)(W1T + col * 8);
        float4 w1b = *(const float4*)(W1T + col * 8 + 4);
        float bb = b1[col];
        #pragma unroll
        for (int r = 0; r < 8; ++r) {
            int e = wv * 8 + r;
            const float4* efp = (const float4*)ef_s[e];
            float4 f0 = efp[0], f1 = efp[1];
            float s = bb + f0.x * w1a.x + f0.y * w1a.y + f0.z * w1a.z + f0.w * w1a.w
                        + f1.x * w1b.x + f1.y * w1b.y + f1.z * w1b.z + f1.w * w1b.w;
            ha[e][col] = s / (1.f + expf(-s));
        }
    }
    __syncthreads();
    {
        const float4* wp = (const float4*)(W2T + col * 64);
        float4 wc[16];
        #pragma unroll
        for (int i = 0; i < 16; ++i) wc[i] = wp[i];
        float bb = b2[col];
        #pragma unroll
        for (int r = 0; r < 8; ++r) {
            int e = wv * 8 + r;
            const float4* hp = (const float4*)ha[e];
            float s = bb;
            #pragma unroll
            for (int i = 0; i < 16; ++i) {
                float4 h4 = hp[i];
                s += h4.x * wc[i].x + h4.y * wc[i].y + h4.z * wc[i].z + h4.w * wc[i].w;
            }
            hb[e][col] = s / (1.f + expf(-s));
        }
    }
    __syncthreads();
    {
        const float4* wp = (const float4*)(W3T + col * 64);
        float4 wc[16];
        #pragma unroll
        for (int i = 0; i < 16; ++i) wc[i] = wp[i];
        float bb = b3[col];
        #pragma unroll
        for (int r = 0; r < 8; ++r) {
            int e = wv * 8 + r;
            const float4* hp = (const float4*)hb[e];
            float s = bb;
            #pragma unroll
            for (int i = 0; i < 16; ++i) {
                float4 h4 = hp[i];
                s += h4.x * wc[i].x + h4.y * wc[i].y + h4.z * wc[i].z + h4.w * wc[i].w;
            }
            ha[e][col] = s / (1.f + expf(-s));
        }
    }
    __syncthreads();
    {
        int i0 = t * 8;
        int e = i0 >> 6, k = i0 & 63;
        const float* hp = &ha[e][k];
        u16x8 vh, vl;
        #pragma unroll
        for (int r = 0; r < 8; ++r) {
            float v = hp[r];
            unsigned h = bf16_rne(v);
            float fh = __uint_as_float(h << 16);
            unsigned lo = bf16_rne(v - fh);
            vh[r] = (u16)h;
            vl[r] = (u16)lo;
        }
        *(u16x8*)&HFh[e * 72 + k] = vh;
        *(u16x8*)&HFl[e * 72 + k] = vl;
    }
    __syncthreads();
    int lane = t & 63;
    int eloc = lane & 15, kq = lane >> 4;
    int ntile = wv & 1, mhalf = wv >> 1;
    int e = ntile * 16 + eloc;
    const u16* hfh = &HFh[e * 72 + kq * 8];
    const u16* hfl = &HFl[e * 72 + kq * 8];
    bf16x8 bH0 = *(const bf16x8*)hfh;
    bf16x8 bH1 = *(const bf16x8*)(hfh + 32);
    bf16x8 bL0 = *(const bf16x8*)hfl;
    bf16x8 bL1 = *(const bf16x8*)(hfl + 32);
    const float* xrow = x + (size_t)srcs[e] * 128;
    float* arow = A + (size_t)(e0 + e) * 512;
    #pragma unroll 2
    for (int mt = 0; mt < 16; ++mt) {
        int m0 = mhalf * 256 + mt * 16;
        const u16* ap  = W4Th + (m0 + eloc) * 64 + kq * 8;
        const u16* apl = W4Tl + (m0 + eloc) * 64 + kq * 8;
        bf16x8 aH0 = *(const bf16x8*)ap;
        bf16x8 aH1 = *(const bf16x8*)(ap + 32);
        bf16x8 aL0 = *(const bf16x8*)apl;
        bf16x8 aL1 = *(const bf16x8*)(apl + 32);
        f32x4 a4 = (f32x4){0.f, 0.f, 0.f, 0.f};
        a4 = __builtin_amdgcn_mfma_f32_16x16x32_bf16(aH0, bH0, a4, 0, 0, 0);
        a4 = __builtin_amdgcn_mfma_f32_16x16x32_bf16(aH1, bH1, a4, 0, 0, 0);
        a4 = __builtin_amdgcn_mfma_f32_16x16x32_bf16(aH0, bL0, a4, 0, 0, 0);
        a4 = __builtin_amdgcn_mfma_f32_16x16x32_bf16(aH1, bL1, a4, 0, 0, 0);
        a4 = __builtin_amdgcn_mfma_f32_16x16x32_bf16(aL0, bH0, a4, 0, 0, 0);
        a4 = __builtin_amdgcn_mfma_f32_16x16x32_bf16(aL1, bH1, a4, 0, 0, 0);
        int c0 = m0 + kq * 4;                 // D row = kq*4 + reg
        float4 b4v4 = *(const float4*)(b4 + c0);
        float4 xv = *(const float4*)(xrow + (c0 & 127));
        float4 o;
        o.x = (a4[0] + b4v4.x) * xv.x;
        o.y = (a4[1] + b4v4.y) * xv.y;
        o.z = (a4[2] + b4v4.z) * xv.z;
        o.w = (a4[3] + b4v4.w) * xv.w;
        *(float4*)(arow + c0) = o;
    }
}

// ---------------- FUSED BACK-HALF: Y segment-sum -> LDS msgs -> MFMA C-contraction -> out ----------------
// block = 16 same-z nodes. A read coalesced from HBM; msgs split-bf16 in swizzled LDS;
// out written directly (64B contiguous per lane).
__global__ __launch_bounds__(256) void k_back(const float* __restrict__ A,
                                              const float* __restrict__ ea,
                                              const u16* __restrict__ CH,
                                              const u16* __restrict__ CL,
                                              const int* __restrict__ row_start,
                                              const int* __restrict__ elist,
                                              const int* __restrict__ zrs,
                                              const int* __restrict__ znodes,
                                              float* __restrict__ out) {
    int z = blockIdx.x / NT16;
    int tile = blockIdx.x % NT16;
    int base = zrs[z];
    int cz = zrs[z + 1] - base;
    int p0 = tile * 16;
    if (p0 >= cz) return;

    __shared__ u16 mh[16 * 16 * 128];    // 64 KB, swizzled: idx ^ ((n&7)<<3)
    __shared__ u16 ml[16 * 16 * 128];    // 64 KB
    __shared__ float Ys[ECAP2][16];      // 12 KB
    __shared__ int el_s[ECAP2];
    __shared__ int off_s[17];
    __shared__ int rbase_s[16];
    __shared__ int nid_s[16];

    int t = threadIdx.x;
    if (t < 16) {
        int nid = (p0 + t < cz) ? znodes[base + p0 + t] : -1;
        nid_s[t] = nid;
        rbase_s[t] = (nid >= 0) ? row_start[nid] : 0;
    }
    __syncthreads();
    if (t == 0) {
        int run = 0;
        for (int j = 0; j < 16; ++j) {
            off_s[j] = run;
            int nid = nid_s[j];
            int cnt = (nid >= 0) ? (row_start[nid + 1] - rbase_s[j]) : 0;
            run += cnt;
            if (run > ECAP2) run = ECAP2;
        }
        off_s[16] = run;
    }
    __syncthreads();
    // stage edge ids per node
    for (int j = 0; j < 16; ++j) {
        int a0 = off_s[j], a1 = off_s[j + 1];
        for (int i = a0 + t; i < a1; i += 256) el_s[i] = elist[rbase_s[j] + (i - a0)];
    }
    __syncthreads();
    if (t < 16) {   // per-node sort -> deterministic accumulation order
        int a0 = off_s[t], a1 = off_s[t + 1];
        for (int i = a0 + 1; i < a1; ++i) {
            int key = el_s[i]; int j = i - 1;
            while (j >= a0 && el_s[j] > key) { el_s[j + 1] = el_s[j]; --j; }
            el_s[j + 1] = key;
        }
    }
    __syncthreads();
    int kk = off_s[16];
    for (int idx = t; idx < kk * 16; idx += 256) {
        int i = idx >> 4, d = idx & 15;
        Ys[i][d] = ea[(size_t)el_s[i] * 16 + d];
    }
    __syncthreads();

    // ---- phase 1: per-node segment-sum in registers -> split-bf16 msgs in LDS ----
    int u = t & 127;
    int half = t >> 7;          // wave-uniform
    int mb = half * 8;
    for (int j = 0; j < 16; ++j) {
        int a0 = off_s[j], a1 = off_s[j + 1];
        float acc[8];
        #pragma unroll
        for (int q = 0; q < 8; ++q) acc[q] = 0.f;
        for (int p = a0; p < a1; p += 4) {
            float av[4][3];
            float yv[4][8];
            #pragma unroll
            for (int s = 0; s < 4; ++s) {
                int pos = p + s;
                int vld = (pos < a1);
                int pp = vld ? pos : a0;
                const float* Ae = A + (size_t)el_s[pp] * 512;
                if (half == 0) {
                    av[s][0] = Ae[u];
                    av[s][1] = Ae[128 + u];
                    av[s][2] = Ae[256 + u];
                } else {
                    av[s][0] = Ae[256 + u];
                    av[s][1] = Ae[384 + u];
                    av[s][2] = 0.f;
                }
                #pragma unroll
                for (int q = 0; q < 8; ++q) yv[s][q] = vld ? Ys[pp][mb + q] : 0.f;
            }
            #pragma unroll
            for (int s = 0; s < 4; ++s) {
                if (half == 0) {
                    acc[0] += av[s][0] * yv[s][0];
                    acc[1] += av[s][1] * yv[s][1];
                    acc[2] += av[s][1] * yv[s][2];
                    acc[3] += av[s][1] * yv[s][3];
                    acc[4] += av[s][2] * yv[s][4];
                    acc[5] += av[s][2] * yv[s][5];
                    acc[6] += av[s][2] * yv[s][6];
                    acc[7] += av[s][2] * yv[s][7];
                } else {
                    acc[0] += av[s][0] * yv[s][0];
                    #pragma unroll
                    for (int q = 1; q < 8; ++q) acc[q] += av[s][1] * yv[s][q];
                }
            }
        }
        #pragma unroll
        for (int q = 0; q < 8; ++q) {
            int m = mb + q;
            float v = acc[q];
            unsigned h = bf16_rne(v);
            float fh = __uint_as_float(h << 16);
            unsigned lo = bf16_rne(v - fh);
            int idx = (((m * 16 + j) * 128) + u) ^ ((j & 7) << 3);
            mh[idx] = (u16)h;
            ml[idx] = (u16)lo;
        }
    }
    __syncthreads();

    // ---- phase 2: D[u'][n][m] = C_l[z]^T x msgs, per-lane 128-float output regs ----
    int w = t >> 6;
    int lane = t & 63;
    int colq = lane & 15;       // node col
    int krow = lane >> 4;
    int nid = nid_s[colq];
    float4 st[2][4][4];         // [mt][i][m-group], component = m&3
    #pragma unroll
    for (int pl = 0; pl < 16; ++pl) {
        int l = (pl >= 9) ? 3 : (pl >= 4) ? 2 : (pl >= 1) ? 1 : 0;
        int lz = l * 10 + z;
        f32x4 a0 = (f32x4){0.f, 0.f, 0.f, 0.f};
        f32x4 a1 = (f32x4){0.f, 0.f, 0.f, 0.f};
        #pragma unroll
        for (int kt = 0; kt < 4; ++kt) {
            int kc = kt * 4 + krow;
            int bidx = (((pl * 16 + colq) * 128) + kc * 8) ^ ((colq & 7) << 3);
            bf16x8 bH = *(const bf16x8*)&mh[bidx];
            bf16x8 bL = *(const bf16x8*)&ml[bidx];
            size_t abase = ((size_t)(lz * 16 + kc) * 128 + w * 32 + colq) * 8;
            bf16x8 aH0 = *(const bf16x8*)(CH + abase);
            bf16x8 aL0 = *(const bf16x8*)(CL + abase);
            bf16x8 aH1 = *(const bf16x8*)(CH + abase + 128);
            bf16x8 aL1 = *(const bf16x8*)(CL + abase + 128);
            a0 = __builtin_amdgcn_mfma_f32_16x16x32_bf16(aH0, bH, a0, 0, 0, 0);
            a0 = __builtin_amdgcn_mfma_f32_16x16x32_bf16(aH0, bL, a0, 0, 0, 0);
            a0 = __builtin_amdgcn_mfma_f32_16x16x32_bf16(aL0, bH, a0, 0, 0, 0);
            a1 = __builtin_amdgcn_mfma_f32_16x16x32_bf16(aH1, bH, a1, 0, 0, 0);
            a1 = __builtin_amdgcn_mfma_f32_16x16x32_bf16(aH1, bL, a1, 0, 0, 0);
            a1 = __builtin_amdgcn_mfma_f32_16x16x32_bf16(aL1, bH, a1, 0, 0, 0);
        }
        #pragma unroll
        for (int i = 0; i < 4; ++i) {
            st[0][i][pl >> 2][pl & 3] = a0[i];
            st[1][i][pl >> 2][pl & 3] = a1[i];
        }
    }
    if (nid >= 0) {
        float* orow = out + (size_t)nid * 2048;
        #pragma unroll
        for (int mt = 0; mt < 2; ++mt) {
            #pragma unroll
            for (int i = 0; i < 4; ++i) {
                int up = w * 32 + mt * 16 + krow * 4 + i;
                float4* p = (float4*)(orow + up * 16);
                p[0] = st[mt][i][0];
                p[1] = st[mt][i][1];
                p[2] = st[mt][i][2];
                p[3] = st[mt][i][3];
            }
        }
    }
}

extern "C" void kernel_launch(void* const* d_in, const int* in_sizes, int n_in,
                              void* d_out, int out_size, void* d_ws, size_t ws_size,
                              hipStream_t stream) {
    const float* na   = (const float*)d_in[0];
    const float* nf   = (const float*)d_in[1];
    const float* ea   = (const float*)d_in[2];
    const float* ef   = (const float*)d_in[3];
    const int*   eidx = (const int*)d_in[4];
    const float* Wup  = (const float*)d_in[5];
    const float* W1   = (const float*)d_in[6];
    const float* b1   = (const float*)d_in[7];
    const float* W2   = (const float*)d_in[8];
    const float* b2   = (const float*)d_in[9];
    const float* W3   = (const float*)d_in[10];
    const float* b3   = (const float*)d_in[11];
    const float* W4   = (const float*)d_in[12];
    const float* b4   = (const float*)d_in[13];
    const float* Wlin = (const float*)d_in[14];
    const float* Wskip= (const float*)d_in[15];
    float* out = (float*)d_out;

    char* ws = (char*)d_ws;
    float* A        = (float*)(ws + WS_R1);
    float* x        = (float*)(ws + WS_X);
    u16*   CH       = (u16*)(ws + WS_CH);
    u16*   CL       = (u16*)(ws + WS_CL);
    int*   counts   = (int*)(ws + WS_COUNTS);   // becomes cursor after k_scan
    int*   zcnt     = (int*)(ws + WS_ZCNT);
    int*   rowstart = (int*)(ws + WS_ROWSTART);
    int*   zrs      = (int*)(ws + WS_ZRS);
    int*   zcur     = (int*)(ws + WS_ZCUR);
    int*   elist    = (int*)(ws + WS_ELIST);
    int*   znodes   = (int*)(ws + WS_ZNODES);

    // d_out scratch: prep weights (k_prep -> k_edge); fully overwritten by k_back's out
    float* W1T  = (float*)d_out;
    float* W2T  = W1T + 512;
    float* W3T  = W1T + 4608;
    u16*   W4Th = (u16*)((char*)d_out + 34816);
    u16*   W4Tl = (u16*)((char*)d_out + 100352);

    hipMemsetAsync(counts, 0, 32768 + 64, stream);  // counts + zcnt
    k_prep<<<128, 256, 0, stream>>>(W1, W2, W3, W4, W1T, W2T, W3T, W4Th, W4Tl);
    k_count<<<NE / 256, 256, 0, stream>>>(eidx, na, counts, zcnt);
    k_scan<<<1, 1024, 0, stream>>>(counts, rowstart, zcnt, zrs, zcur);
    k_scatter<<<NE / 256, 256, 0, stream>>>(eidx, na, counts, elist, zcur, znodes);
    k_x<<<NN / 16, 256, 0, stream>>>(nf, Wup, x);
    k_C<<<320, 256, 0, stream>>>(Wlin, Wskip, CH, CL);
    k_edge<<<NE / 32, 256, 0, stream>>>(ef, eidx, b1, b2, b3, b4,
                                        W1T, W2T, W3T, W4Th, W4Tl, x, A);
    k_back<<<10 * NT16, 256, 0, stream>>>(A, ea, CH, CL, rowstart, elist, zrs, znodes, out);
}

// Round 8
// 359.175 us; speedup vs baseline: 1.1543x; 1.1543x over previous
//
#include <hip/hip_runtime.h>
#include <math.h>

#define NE 65536
#define NN 8192
#define NT4 240      // 4-node tiles per z (240*4=960 >= max z-group ~900)
#define GCAP 128     // max staged edges per 4-node block (mean 32; huge margin)

typedef unsigned short u16;
typedef float f32x4 __attribute__((ext_vector_type(4)));
typedef __bf16 bf16x8 __attribute__((ext_vector_type(8)));
typedef unsigned short u16x8 __attribute__((ext_vector_type(8)));

// ---- ws layout (bytes); total within 141,394,072 (proven safe R1-R7) ----
#define WS_A        0u           // 134,217,728: A[e][512] f32 (k_edge -> k_gather4)
#define WS_X        134217728u   // 4,194,304
#define WS_C        138412032u   // 2,621,440  C f32 [lz=40][u=128][u2=128] -> ends 141,033,472
#define WS_COUNTS   141033472u   // 32,768 (counts; becomes cursor after k_scan)
#define WS_ZCNT     141066240u   // 64
#define WS_ROWSTART 141066304u   // 32,772
#define WS_ZRS      141099076u   // 44 (11 ints)
#define WS_ZCUR     141099120u   // 40
#define WS_ELIST    141099160u   // 262,144
#define WS_ZNODES   141361304u   // 32,768 -> end 141,394,072

// ---- d_out scratch for k_prep weights (k_prep -> k_edge; fully overwritten by k_gather4) ----
__device__ __forceinline__ unsigned bf16_rne(float v) {
    unsigned u = __float_as_uint(v);
    return (u + 0x7FFFu + ((u >> 16) & 1u)) >> 16;
}

__device__ __forceinline__ float silu_f(float s) {
    return s * __builtin_amdgcn_rcpf(1.f + __expf(-s));   // validated R6 (absmax unchanged)
}

// ---------------- CSR build (edge by dst) + z-grouping of nodes ----------------
__global__ void k_count(const int* __restrict__ eidx, const float* __restrict__ na,
                        int* __restrict__ counts, int* __restrict__ zcnt) {
    int e = blockIdx.x * 256 + threadIdx.x;
    if (e < NE) atomicAdd(&counts[eidx[NE + e]], 1);
    if (e < NN) {
        const float* row = na + (size_t)e * 10;
        int z = 0;
        #pragma unroll
        for (int w = 1; w < 10; ++w) if (row[w] > 0.5f) z = w;
        atomicAdd(&zcnt[z], 1);
    }
}

__global__ __launch_bounds__(1024) void k_scan(int* __restrict__ counts,  // also becomes cursor
                                               int* __restrict__ row_start,
                                               const int* __restrict__ zcnt,
                                               int* __restrict__ zrs, int* __restrict__ zcur) {
    __shared__ int sd[1024];
    int t = threadIdx.x;
    int c[8];
    int s = 0;
    #pragma unroll
    for (int i = 0; i < 8; ++i) { c[i] = counts[t * 8 + i]; s += c[i]; }
    sd[t] = s;
    __syncthreads();
    for (int off = 1; off < 1024; off <<= 1) {
        int v = (t >= off) ? sd[t - off] : 0;
        __syncthreads();
        sd[t] += v;
        __syncthreads();
    }
    int run = (t == 0) ? 0 : sd[t - 1];
    #pragma unroll
    for (int i = 0; i < 8; ++i) {
        row_start[t * 8 + i] = run;
        counts[t * 8 + i] = run;   // cursor
        run += c[i];
    }
    if (t == 1023) row_start[8192] = run;
    if (t == 0) {
        int zr = 0;
        for (int i = 0; i < 10; ++i) { zrs[i] = zr; zcur[i] = zr; zr += zcnt[i]; }
        zrs[10] = zr;
    }
}

__global__ void k_scatter(const int* __restrict__ eidx, const float* __restrict__ na,
                          int* __restrict__ cursor, int* __restrict__ elist,
                          int* __restrict__ zcur, int* __restrict__ znodes) {
    int e = blockIdx.x * 256 + threadIdx.x;
    if (e < NE) {
        int p = atomicAdd(&cursor[eidx[NE + e]], 1);
        elist[p] = e;
    }
    if (e < NN) {
        const float* row = na + (size_t)e * 10;
        int z = 0;
        #pragma unroll
        for (int w = 1; w < 10; ++w) if (row[w] > 0.5f) z = w;
        int p = atomicAdd(&zcur[z], 1);
        znodes[p] = e;
    }
}

// ---------------- weight prep -> d_out scratch ----------------
__global__ __launch_bounds__(256) void k_prep(const float* __restrict__ W1, const float* __restrict__ W2,
                                              const float* __restrict__ W3, const float* __restrict__ W4,
                                              float* __restrict__ W1T, float* __restrict__ W2T,
                                              float* __restrict__ W3T, u16* __restrict__ W4Th,
                                              u16* __restrict__ W4Tl) {
    int t = blockIdx.x * 256 + threadIdx.x;
    if (t < 512) { int c = t >> 3, k = t & 7; W1T[t] = W1[k * 64 + c]; }
    if (t < 4096) {
        int c = t >> 6, k = t & 63;
        W2T[t] = W2[k * 64 + c];
        W3T[t] = W3[k * 64 + c];
    }
    if (t < 32768) {
        int c = t >> 6, k = t & 63;
        float v = W4[k * 512 + c];
        unsigned h = bf16_rne(v);
        float fh = __uint_as_float(h << 16);
        unsigned lo = bf16_rne(v - fh);
        W4Th[t] = (u16)h;
        W4Tl[t] = (u16)lo;
    }
}

// ---------------- x = node_feats @ W_up / sqrt(128) ----------------
__global__ __launch_bounds__(256) void k_x(const float* __restrict__ nf,
                                           const float* __restrict__ Wup,
                                           float* __restrict__ x) {
    __shared__ float nf_s[16][128];
    int n0 = blockIdx.x * 16;
    int t = threadIdx.x;
    for (int i = t; i < 16 * 128; i += 256) nf_s[i >> 7][i & 127] = nf[n0 * 128 + i];
    __syncthreads();
    int mc = t & 127, half = t >> 7;
    float acc[8];
    #pragma unroll
    for (int j = 0; j < 8; ++j) acc[j] = 0.f;
    for (int k = 0; k < 128; ++k) {
        float w = Wup[k * 128 + mc];
        #pragma unroll
        for (int j = 0; j < 8; ++j) acc[j] += nf_s[half * 8 + j][k] * w;
    }
    const float rs = 0.08838834764831845f;  // 1/sqrt(128)
    #pragma unroll
    for (int j = 0; j < 8; ++j) x[(n0 + half * 8 + j) * 128 + mc] = acc[j] * rs;
}

// ---------------- C[lz][u][u2] f32 = scale * sum_v W_lin[l][u][v] * W_skip[l][v][z][u2] ----------------
__global__ __launch_bounds__(256) void k_C(const float* __restrict__ Wlin,
                                           const float* __restrict__ Wskip,
                                           float* __restrict__ C) {
    __shared__ float wl_s[16][128];
    int b = blockIdx.x;
    int lz = b >> 3, ut = b & 7;
    int l = lz / 10, z = lz % 10;
    int t = threadIdx.x;
    for (int i = t; i < 16 * 128; i += 256) {
        int u = i >> 7, v = i & 127;
        wl_s[u][v] = Wlin[(l * 128 + ut * 16 + u) * 128 + v];
    }
    __syncthreads();
    int u2 = t & 127, uh = t >> 7;
    float acc[8];
    #pragma unroll
    for (int r = 0; r < 8; ++r) acc[r] = 0.f;
    const float* Wsk = Wskip + ((size_t)l * 128 * 10 + z) * 128 + u2;  // stride over v: 1280
    for (int v = 0; v < 128; v += 4) {
        float s0 = Wsk[(size_t)(v + 0) * 1280];
        float s1 = Wsk[(size_t)(v + 1) * 1280];
        float s2 = Wsk[(size_t)(v + 2) * 1280];
        float s3 = Wsk[(size_t)(v + 3) * 1280];
        #pragma unroll
        for (int r = 0; r < 8; ++r) {
            int u = uh * 8 + r;
            acc[r] += wl_s[u][v] * s0 + wl_s[u][v + 1] * s1
                    + wl_s[u][v + 2] * s2 + wl_s[u][v + 3] * s3;
        }
    }
    const float scale = 3.0881618e-04f;  // (1/sqrt(128)/8) * (1/sqrt(1280))
    #pragma unroll
    for (int r = 0; r < 8; ++r) {
        int u = ut * 16 + uh * 8 + r;
        C[((size_t)(l * 10 + z) * 128 + u) * 128 + u2] = acc[r] * scale;
    }
}

// ---------------- edge MLP (weights-in-VGPR) + W4 GEMM (split-bf16 MFMA) -> A ----------------
__global__ __launch_bounds__(256) void k_edge(const float* __restrict__ ef,
                                              const int* __restrict__ eidx,
                                              const float* __restrict__ b1, const float* __restrict__ b2,
                                              const float* __restrict__ b3, const float* __restrict__ b4,
                                              const float* __restrict__ W1T, const float* __restrict__ W2T,
                                              const float* __restrict__ W3T,
                                              const u16* __restrict__ W4Th, const u16* __restrict__ W4Tl,
                                              const float* __restrict__ x,
                                              float* __restrict__ A) {
    __shared__ float ef_s[32][8];
    __shared__ float ha[32][64];
    __shared__ float hb[32][64];
    __shared__ u16 HFh[32 * 72];
    __shared__ u16 HFl[32 * 72];
    __shared__ int srcs[32];
    int t = threadIdx.x;
    int e0 = blockIdx.x * 32;
    ef_s[t >> 3][t & 7] = ef[e0 * 8 + t];
    if (t < 32) srcs[t] = eidx[e0 + t];
    __syncthreads();
    int col = t & 63, wv = t >> 6;
    {
        float4 w1a = *(const float4*)(W1T + col * 8);
        float4 w1b = *(const float4*)(W1T + col * 8 + 4);
        float bb = b1[col];
        #pragma unroll
        for (int r = 0; r < 8; ++r) {
            int e = wv * 8 + r;
            const float4* efp = (const float4*)ef_s[e];
            float4 f0 = efp[0], f1 = efp[1];
            float s = bb + f0.x * w1a.x + f0.y * w1a.y + f0.z * w1a.z + f0.w * w1a.w
                        + f1.x * w1b.x + f1.y * w1b.y + f1.z * w1b.z + f1.w * w1b.w;
            ha[e][col] = silu_f(s);
        }
    }
    __syncthreads();
    {
        const float4* wp = (const float4*)(W2T + col * 64);
        float4 wc[16];
        #pragma unroll
        for (int i = 0; i < 16; ++i) wc[i] = wp[i];
        float bb = b2[col];
        #pragma unroll
        for (int r = 0; r < 8; ++r) {
            int e = wv * 8 + r;
            const float4* hp = (const float4*)ha[e];
            float s = bb;
            #pragma unroll
            for (int i = 0; i < 16; ++i) {
                float4 h4 = hp[i];
                s += h4.x * wc[i].x + h4.y * wc[i].y + h4.z * wc[i].z + h4.w * wc[i].w;
            }
            hb[e][col] = silu_f(s);
        }
    }
    __syncthreads();
    {
        const float4* wp = (const float4*)(W3T + col * 64);
        float4 wc[16];
        #pragma unroll
        for (int i = 0; i < 16; ++i) wc[i] = wp[i];
        float bb = b3[col];
        #pragma unroll
        for (int r = 0; r < 8; ++r) {
            int e = wv * 8 + r;
            const float4* hp = (const float4*)hb[e];
            float s = bb;
            #pragma unroll
            for (int i = 0; i < 16; ++i) {
                float4 h4 = hp[i];
                s += h4.x * wc[i].x + h4.y * wc[i].y + h4.z * wc[i].z + h4.w * wc[i].w;
            }
            ha[e][col] = silu_f(s);
        }
    }
    __syncthreads();
    {
        int i0 = t * 8;
        int e = i0 >> 6, k = i0 & 63;
        const float* hp = &ha[e][k];
        u16x8 vh, vl;
        #pragma unroll
        for (int r = 0; r < 8; ++r) {
            float v = hp[r];
            unsigned h = bf16_rne(v);
            float fh = __uint_as_float(h << 16);
            unsigned lo = bf16_rne(v - fh);
            vh[r] = (u16)h;
            vl[r] = (u16)lo;
        }
        *(u16x8*)&HFh[e * 72 + k] = vh;
        *(u16x8*)&HFl[e * 72 + k] = vl;
    }
    __syncthreads();
    int lane = t & 63;
    int eloc = lane & 15, kq = lane >> 4;
    int ntile = wv & 1, mhalf = wv >> 1;
    int e = ntile * 16 + eloc;
    const u16* hfh = &HFh[e * 72 + kq * 8];
    const u16* hfl = &HFl[e * 72 + kq * 8];
    bf16x8 bH0 = *(const bf16x8*)hfh;
    bf16x8 bH1 = *(const bf16x8*)(hfh + 32);
    bf16x8 bL0 = *(const bf16x8*)hfl;
    bf16x8 bL1 = *(const bf16x8*)(hfl + 32);
    const float* xrow = x + (size_t)srcs[e] * 128;
    float* arow = A + (size_t)(e0 + e) * 512;
    #pragma unroll 2
    for (int mt = 0; mt < 16; ++mt) {
        int m0 = mhalf * 256 + mt * 16;
        const u16* ap  = W4Th + (m0 + eloc) * 64 + kq * 8;
        const u16* apl = W4Tl + (m0 + eloc) * 64 + kq * 8;
        bf16x8 aH0 = *(const bf16x8*)ap;
        bf16x8 aH1 = *(const bf16x8*)(ap + 32);
        bf16x8 aL0 = *(const bf16x8*)apl;
        bf16x8 aL1 = *(const bf16x8*)(apl + 32);
        f32x4 a4 = (f32x4){0.f, 0.f, 0.f, 0.f};
        a4 = __builtin_amdgcn_mfma_f32_16x16x32_bf16(aH0, bH0, a4, 0, 0, 0);
        a4 = __builtin_amdgcn_mfma_f32_16x16x32_bf16(aH1, bH1, a4, 0, 0, 0);
        a4 = __builtin_amdgcn_mfma_f32_16x16x32_bf16(aH0, bL0, a4, 0, 0, 0);
        a4 = __builtin_amdgcn_mfma_f32_16x16x32_bf16(aH1, bL1, a4, 0, 0, 0);
        a4 = __builtin_amdgcn_mfma_f32_16x16x32_bf16(aL0, bH0, a4, 0, 0, 0);
        a4 = __builtin_amdgcn_mfma_f32_16x16x32_bf16(aL1, bH1, a4, 0, 0, 0);
        int c0 = m0 + kq * 4;                 // D row = kq*4 + reg
        float4 b4v4 = *(const float4*)(b4 + c0);
        float4 xv = *(const float4*)(xrow + (c0 & 127));
        float4 o;
        o.x = (a4[0] + b4v4.x) * xv.x;
        o.y = (a4[1] + b4v4.y) * xv.y;
        o.z = (a4[2] + b4v4.z) * xv.z;
        o.w = (a4[3] + b4v4.w) * xv.w;
        *(float4*)(arow + c0) = o;
    }
}

// ---------------- gather + contraction: 4 same-z nodes per block (R2 structure + C reuse) ----------------
// phase1: per-node Y segment-sum -> msgs in LDS (stride 20: b128-aligned broadcast reads)
// phase2: o[n][u2][m] = sum_u msgs[u][m] * C_l[z][u][u2], C amortized over 4 nodes, direct store
__global__ __launch_bounds__(256) void k_gather4(const float* __restrict__ A,
                                                 const float* __restrict__ Y,
                                                 const float* __restrict__ C,
                                                 const int* __restrict__ row_start,
                                                 const int* __restrict__ elist,
                                                 const int* __restrict__ zrs,
                                                 const int* __restrict__ znodes,
                                                 float* __restrict__ out) {
    int z = blockIdx.x / NT4;
    int tile = blockIdx.x % NT4;
    int base = zrs[z], cz = zrs[z + 1] - base;
    int p0 = tile * 4;
    if (p0 >= cz) return;

    __shared__ float msgs_s[4][128 * 20];   // 40 KB
    __shared__ int el_s[GCAP];
    __shared__ int off_s[5];
    __shared__ int nid_s[4];

    int t = threadIdx.x;
    if (t < 4) nid_s[t] = (p0 + t < cz) ? znodes[base + p0 + t] : -1;
    __syncthreads();
    if (t == 0) {
        int run = 0;
        for (int j = 0; j < 4; ++j) {
            off_s[j] = run;
            int nid = nid_s[j];
            int cnt = (nid >= 0) ? (row_start[nid + 1] - row_start[nid]) : 0;
            run += cnt;
            if (run > GCAP) run = GCAP;
        }
        off_s[4] = run;
    }
    __syncthreads();
    for (int j = 0; j < 4; ++j) {
        int a0 = off_s[j], a1 = off_s[j + 1];
        int nid = nid_s[j];
        int rb = (nid >= 0) ? row_start[nid] : 0;
        for (int i = a0 + t; i < a1; i += 256) el_s[i] = elist[rb + (i - a0)];
    }
    __syncthreads();
    if (t < 4) {   // per-node sort -> deterministic accumulation order (matches R2)
        int a0 = off_s[t], a1 = off_s[t + 1];
        for (int i = a0 + 1; i < a1; ++i) {
            int key = el_s[i]; int j = i - 1;
            while (j >= a0 && el_s[j] > key) { el_s[j + 1] = el_s[j]; --j; }
            el_s[j + 1] = key;
        }
    }
    __syncthreads();

    int mc = t & 127, hi = t >> 7;
    // ---- phase 1: per-node segment-sum (identical math/order to R2's k_gather) ----
    for (int j = 0; j < 4; ++j) {
        float acc[8];
        #pragma unroll
        for (int q = 0; q < 8; ++q) acc[q] = 0.f;
        int a0 = off_s[j], a1 = off_s[j + 1];
        for (int p = a0; p < a1; ++p) {
            int e = el_s[p];
            const float* Ae = A + (size_t)e * 512;
            const float* Ye = Y + (size_t)e * 16 + hi * 8;
            float y[8];
            #pragma unroll
            for (int q = 0; q < 8; ++q) y[q] = Ye[q];
            if (hi == 0) {
                float a0v = Ae[mc], a1v = Ae[128 + mc], a2v = Ae[256 + mc];
                acc[0] += a0v * y[0];
                acc[1] += a1v * y[1]; acc[2] += a1v * y[2]; acc[3] += a1v * y[3];
                acc[4] += a2v * y[4]; acc[5] += a2v * y[5]; acc[6] += a2v * y[6]; acc[7] += a2v * y[7];
            } else {
                float a2v = Ae[256 + mc], a3v = Ae[384 + mc];
                acc[0] += a2v * y[0];
                #pragma unroll
                for (int q = 1; q < 8; ++q) acc[q] += a3v * y[q];
            }
        }
        float* mrow = &msgs_s[j][mc * 20 + hi * 8];
        #pragma unroll
        for (int q = 0; q < 8; ++q) mrow[q] = acc[q];
    }
    __syncthreads();

    // ---- phase 2: contraction, C loads amortized over 4 nodes ----
    float o[4][8];
    #pragma unroll
    for (int j = 0; j < 4; ++j)
        #pragma unroll
        for (int q = 0; q < 8; ++q) o[j][q] = 0.f;
    if (hi == 0) {
        const float* C0 = C + (size_t)(0 * 10 + z) * 16384 + mc;
        const float* C1 = C + (size_t)(1 * 10 + z) * 16384 + mc;
        const float* C2 = C + (size_t)(2 * 10 + z) * 16384 + mc;
        for (int u = 0; u < 128; ++u) {
            float c0 = C0[u * 128], c1 = C1[u * 128], c2 = C2[u * 128];
            #pragma unroll
            for (int j = 0; j < 4; ++j) {
                const float4* mp = (const float4*)&msgs_s[j][u * 20];
                float4 m0 = mp[0], m1 = mp[1];
                o[j][0] += m0.x * c0;
                o[j][1] += m0.y * c1; o[j][2] += m0.z * c1; o[j][3] += m0.w * c1;
                o[j][4] += m1.x * c2; o[j][5] += m1.y * c2; o[j][6] += m1.z * c2; o[j][7] += m1.w * c2;
            }
        }
    } else {
        const float* C2 = C + (size_t)(2 * 10 + z) * 16384 + mc;
        const float* C3 = C + (size_t)(3 * 10 + z) * 16384 + mc;
        for (int u = 0; u < 128; ++u) {
            float c2 = C2[u * 128], c3 = C3[u * 128];
            #pragma unroll
            for (int j = 0; j < 4; ++j) {
                const float4* mp = (const float4*)&msgs_s[j][u * 20 + 8];
                float4 m0 = mp[0], m1 = mp[1];
                o[j][0] += m0.x * c2;
                o[j][1] += m0.y * c3; o[j][2] += m0.z * c3; o[j][3] += m0.w * c3;
                o[j][4] += m1.x * c3; o[j][5] += m1.y * c3; o[j][6] += m1.z * c3; o[j][7] += m1.w * c3;
            }
        }
    }
    // ---- direct store: out[nid][u2=mc][m=hi*8+q], two float4 per (thread,node) ----
    #pragma unroll
    for (int j = 0; j < 4; ++j) {
        int nid = nid_s[j];
        if (nid < 0) continue;
        float4 v0 = make_float4(o[j][0], o[j][1], o[j][2], o[j][3]);
        float4 v1 = make_float4(o[j][4], o[j][5], o[j][6], o[j][7]);
        float4* dst = (float4*)(out + (size_t)nid * 2048 + mc * 16 + hi * 8);
        dst[0] = v0;
        dst[1] = v1;
    }
}

extern "C" void kernel_launch(void* const* d_in, const int* in_sizes, int n_in,
                              void* d_out, int out_size, void* d_ws, size_t ws_size,
                              hipStream_t stream) {
    const float* na   = (const float*)d_in[0];
    const float* nf   = (const float*)d_in[1];
    const float* ea   = (const float*)d_in[2];
    const float* ef   = (const float*)d_in[3];
    const int*   eidx = (const int*)d_in[4];
    const float* Wup  = (const float*)d_in[5];
    const float* W1   = (const float*)d_in[6];
    const float* b1   = (const float*)d_in[7];
    const float* W2   = (const float*)d_in[8];
    const float* b2   = (const float*)d_in[9];
    const float* W3   = (const float*)d_in[10];
    const float* b3   = (const float*)d_in[11];
    const float* W4   = (const float*)d_in[12];
    const float* b4   = (const float*)d_in[13];
    const float* Wlin = (const float*)d_in[14];
    const float* Wskip= (const float*)d_in[15];
    float* out = (float*)d_out;

    char* ws = (char*)d_ws;
    float* A        = (float*)(ws + WS_A);
    float* x        = (float*)(ws + WS_X);
    float* C        = (float*)(ws + WS_C);
    int*   counts   = (int*)(ws + WS_COUNTS);   // becomes cursor after k_scan
    int*   zcnt     = (int*)(ws + WS_ZCNT);
    int*   rowstart = (int*)(ws + WS_ROWSTART);
    int*   zrs      = (int*)(ws + WS_ZRS);
    int*   zcur     = (int*)(ws + WS_ZCUR);
    int*   elist    = (int*)(ws + WS_ELIST);
    int*   znodes   = (int*)(ws + WS_ZNODES);

    // d_out scratch: prep weights (k_prep -> k_edge); fully overwritten by k_gather4
    float* W1T  = (float*)d_out;
    float* W2T  = W1T + 512;
    float* W3T  = W1T + 4608;
    u16*   W4Th = (u16*)((char*)d_out + 34816);
    u16*   W4Tl = (u16*)((char*)d_out + 100352);

    hipMemsetAsync(counts, 0, 32768 + 64, stream);  // counts + zcnt
    k_prep<<<128, 256, 0, stream>>>(W1, W2, W3, W4, W1T, W2T, W3T, W4Th, W4Tl);
    k_count<<<NE / 256, 256, 0, stream>>>(eidx, na, counts, zcnt);
    k_scan<<<1, 1024, 0, stream>>>(counts, rowstart, zcnt, zrs, zcur);
    k_scatter<<<NE / 256, 256, 0, stream>>>(eidx, na, counts, elist, zcur, znodes);
    k_x<<<NN / 16, 256, 0, stream>>>(nf, Wup, x);
    k_C<<<320, 256, 0, stream>>>(Wlin, Wskip, C);
    k_edge<<<NE / 32, 256, 0, stream>>>(ef, eidx, b1, b2, b3, b4,
                                        W1T, W2T, W3T, W4Th, W4Tl, x, A);
    k_gather4<<<10 * NT4, 256, 0, stream>>>(A, ea, C, rowstart, elist, zrs, znodes, out);
}

// Round 9
// 337.874 us; speedup vs baseline: 1.2271x; 1.0630x over previous
//
#include <hip/hip_runtime.h>
#include <math.h>

#define NE 65536
#define NN 8192
#define NT2 480      // 2-node tiles per z (480*2=960 >= max z-group, proven R8)
#define GCAP2 96     // max edges per 2-node block (mean 16)
#define SCAP 3072    // k_sort staging (256 nodes, mean 2048 edges)

typedef unsigned short u16;
typedef float f32x4 __attribute__((ext_vector_type(4)));
typedef __bf16 bf16x8 __attribute__((ext_vector_type(8)));
typedef unsigned short u16x8 __attribute__((ext_vector_type(8)));

// ---- ws layout (bytes); total within 141,394,072 (proven safe R1-R8) ----
#define WS_A        0u           // 134,217,728: A[p][512] f32, p = elist position (k_edge -> k_gather2)
#define WS_X        134217728u   // 4,194,304
#define WS_C        138412032u   // 2,621,440  C f32 [lz=40][u=128][u2=128]
#define WS_COUNTS   141033472u   // 32,768 (counts; becomes cursor after k_scan)
#define WS_ZCNT     141066240u   // 64
#define WS_ROWSTART 141066304u   // 32,772
#define WS_ZRS      141099076u   // 44 (11 ints)
#define WS_ZCUR     141099120u   // 40
#define WS_ELIST    141099160u   // 262,144
#define WS_ZNODES   141361304u   // 32,768 -> end 141,394,072

__device__ __forceinline__ unsigned bf16_rne(float v) {
    unsigned u = __float_as_uint(v);
    return (u + 0x7FFFu + ((u >> 16) & 1u)) >> 16;
}

__device__ __forceinline__ float silu_f(float s) {
    return s * __builtin_amdgcn_rcpf(1.f + __expf(-s));   // validated R6-R8 (absmax unchanged)
}

// ---------------- CSR build (edge by dst) + z-grouping of nodes ----------------
__global__ void k_count(const int* __restrict__ eidx, const float* __restrict__ na,
                        int* __restrict__ counts, int* __restrict__ zcnt) {
    int e = blockIdx.x * 256 + threadIdx.x;
    if (e < NE) atomicAdd(&counts[eidx[NE + e]], 1);
    if (e < NN) {
        const float* row = na + (size_t)e * 10;
        int z = 0;
        #pragma unroll
        for (int w = 1; w < 10; ++w) if (row[w] > 0.5f) z = w;
        atomicAdd(&zcnt[z], 1);
    }
}

__global__ __launch_bounds__(1024) void k_scan(int* __restrict__ counts,  // also becomes cursor
                                               int* __restrict__ row_start,
                                               const int* __restrict__ zcnt,
                                               int* __restrict__ zrs, int* __restrict__ zcur) {
    __shared__ int sd[1024];
    int t = threadIdx.x;
    int c[8];
    int s = 0;
    #pragma unroll
    for (int i = 0; i < 8; ++i) { c[i] = counts[t * 8 + i]; s += c[i]; }
    sd[t] = s;
    __syncthreads();
    for (int off = 1; off < 1024; off <<= 1) {
        int v = (t >= off) ? sd[t - off] : 0;
        __syncthreads();
        sd[t] += v;
        __syncthreads();
    }
    int run = (t == 0) ? 0 : sd[t - 1];
    #pragma unroll
    for (int i = 0; i < 8; ++i) {
        row_start[t * 8 + i] = run;
        counts[t * 8 + i] = run;   // cursor
        run += c[i];
    }
    if (t == 1023) row_start[8192] = run;
    if (t == 0) {
        int zr = 0;
        for (int i = 0; i < 10; ++i) { zrs[i] = zr; zcur[i] = zr; zr += zcnt[i]; }
        zrs[10] = zr;
    }
}

__global__ void k_scatter(const int* __restrict__ eidx, const float* __restrict__ na,
                          int* __restrict__ cursor, int* __restrict__ elist,
                          int* __restrict__ zcur, int* __restrict__ znodes) {
    int e = blockIdx.x * 256 + threadIdx.x;
    if (e < NE) {
        int p = atomicAdd(&cursor[eidx[NE + e]], 1);
        elist[p] = e;
    }
    if (e < NN) {
        const float* row = na + (size_t)e * 10;
        int z = 0;
        #pragma unroll
        for (int w = 1; w < 10; ++w) if (row[w] > 0.5f) z = w;
        int p = atomicAdd(&zcur[z], 1);
        znodes[p] = e;
    }
}

// ---------------- canonicalize elist: per-node ascending sort (determinism) ----------------
__global__ __launch_bounds__(256) void k_sort(const int* __restrict__ row_start,
                                              int* __restrict__ elist) {
    __shared__ int buf[SCAP];
    int n0 = blockIdx.x * 256;
    int t = threadIdx.x;
    int r0 = row_start[n0], r1 = row_start[n0 + 256];
    int len = r1 - r0;
    if (len <= SCAP) {
        for (int i = t; i < len; i += 256) buf[i] = elist[r0 + i];
        __syncthreads();
        int a0 = row_start[n0 + t] - r0, a1 = row_start[n0 + t + 1] - r0;
        for (int i = a0 + 1; i < a1; ++i) {
            int key = buf[i]; int j = i - 1;
            while (j >= a0 && buf[j] > key) { buf[j + 1] = buf[j]; --j; }
            buf[j + 1] = key;
        }
        __syncthreads();
        for (int i = t; i < len; i += 256) elist[r0 + i] = buf[i];
    } else {  // overflow fallback (never for this input)
        int a0 = row_start[n0 + t], a1 = row_start[n0 + t + 1];
        for (int i = a0 + 1; i < a1; ++i) {
            int key = elist[i]; int j = i - 1;
            while (j >= a0 && elist[j] > key) { elist[j + 1] = elist[j]; --j; }
            elist[j + 1] = key;
        }
    }
}

// ---------------- weight prep -> d_out scratch ----------------
__global__ __launch_bounds__(256) void k_prep(const float* __restrict__ W1, const float* __restrict__ W2,
                                              const float* __restrict__ W3, const float* __restrict__ W4,
                                              float* __restrict__ W1T, float* __restrict__ W2T,
                                              float* __restrict__ W3T, u16* __restrict__ W4Th,
                                              u16* __restrict__ W4Tl) {
    int t = blockIdx.x * 256 + threadIdx.x;
    if (t < 512) { int c = t >> 3, k = t & 7; W1T[t] = W1[k * 64 + c]; }
    if (t < 4096) {
        int c = t >> 6, k = t & 63;
        W2T[t] = W2[k * 64 + c];
        W3T[t] = W3[k * 64 + c];
    }
    if (t < 32768) {
        int c = t >> 6, k = t & 63;
        float v = W4[k * 512 + c];
        unsigned h = bf16_rne(v);
        float fh = __uint_as_float(h << 16);
        unsigned lo = bf16_rne(v - fh);
        W4Th[t] = (u16)h;
        W4Tl[t] = (u16)lo;
    }
}

// ---------------- x = node_feats @ W_up / sqrt(128) ----------------
__global__ __launch_bounds__(256) void k_x(const float* __restrict__ nf,
                                           const float* __restrict__ Wup,
                                           float* __restrict__ x) {
    __shared__ float nf_s[16][128];
    int n0 = blockIdx.x * 16;
    int t = threadIdx.x;
    for (int i = t; i < 16 * 128; i += 256) nf_s[i >> 7][i & 127] = nf[n0 * 128 + i];
    __syncthreads();
    int mc = t & 127, half = t >> 7;
    float acc[8];
    #pragma unroll
    for (int j = 0; j < 8; ++j) acc[j] = 0.f;
    for (int k = 0; k < 128; ++k) {
        float w = Wup[k * 128 + mc];
        #pragma unroll
        for (int j = 0; j < 8; ++j) acc[j] += nf_s[half * 8 + j][k] * w;
    }
    const float rs = 0.08838834764831845f;  // 1/sqrt(128)
    #pragma unroll
    for (int j = 0; j < 8; ++j) x[(n0 + half * 8 + j) * 128 + mc] = acc[j] * rs;
}

// ---------------- C[lz][u][u2] f32 ----------------
__global__ __launch_bounds__(256) void k_C(const float* __restrict__ Wlin,
                                           const float* __restrict__ Wskip,
                                           float* __restrict__ C) {
    __shared__ float wl_s[16][128];
    int b = blockIdx.x;
    int lz = b >> 3, ut = b & 7;
    int l = lz / 10, z = lz % 10;
    int t = threadIdx.x;
    for (int i = t; i < 16 * 128; i += 256) {
        int u = i >> 7, v = i & 127;
        wl_s[u][v] = Wlin[(l * 128 + ut * 16 + u) * 128 + v];
    }
    __syncthreads();
    int u2 = t & 127, uh = t >> 7;
    float acc[8];
    #pragma unroll
    for (int r = 0; r < 8; ++r) acc[r] = 0.f;
    const float* Wsk = Wskip + ((size_t)l * 128 * 10 + z) * 128 + u2;  // stride over v: 1280
    for (int v = 0; v < 128; v += 4) {
        float s0 = Wsk[(size_t)(v + 0) * 1280];
        float s1 = Wsk[(size_t)(v + 1) * 1280];
        float s2 = Wsk[(size_t)(v + 2) * 1280];
        float s3 = Wsk[(size_t)(v + 3) * 1280];
        #pragma unroll
        for (int r = 0; r < 8; ++r) {
            int u = uh * 8 + r;
            acc[r] += wl_s[u][v] * s0 + wl_s[u][v + 1] * s1
                    + wl_s[u][v + 2] * s2 + wl_s[u][v + 3] * s3;
        }
    }
    const float scale = 3.0881618e-04f;  // (1/sqrt(128)/8) * (1/sqrt(1280))
    #pragma unroll
    for (int r = 0; r < 8; ++r) {
        int u = ut * 16 + uh * 8 + r;
        C[((size_t)(l * 10 + z) * 128 + u) * 128 + u2] = acc[r] * scale;
    }
}

// ---------------- edge MLP + W4 GEMM (split-bf16 MFMA) -> A[p] in elist order ----------------
__global__ __launch_bounds__(256) void k_edge(const float* __restrict__ ef,
                                              const int* __restrict__ eidx,
                                              const int* __restrict__ elist,
                                              const float* __restrict__ b1, const float* __restrict__ b2,
                                              const float* __restrict__ b3, const float* __restrict__ b4,
                                              const float* __restrict__ W1T, const float* __restrict__ W2T,
                                              const float* __restrict__ W3T,
                                              const u16* __restrict__ W4Th, const u16* __restrict__ W4Tl,
                                              const float* __restrict__ x,
                                              float* __restrict__ A) {
    __shared__ int eid_s[32];
    __shared__ float ef_s[32][8];
    __shared__ float ha[32][64];
    __shared__ float hb[32][64];
    __shared__ u16 HFh[32 * 72];
    __shared__ u16 HFl[32 * 72];
    __shared__ int srcs[32];
    int t = threadIdx.x;
    int e0 = blockIdx.x * 32;
    if (t < 32) eid_s[t] = elist[e0 + t];
    __syncthreads();
    ef_s[t >> 3][t & 7] = ef[(size_t)eid_s[t >> 3] * 8 + (t & 7)];
    if (t < 32) srcs[t] = eidx[eid_s[t]];
    __syncthreads();
    int col = t & 63, wv = t >> 6;
    // ---- layer1: 8 -> 64 ----
    {
        float4 w1a = *(const float4*)(W1T + col * 8);
        float4 w1b = *(const float4*)(W1T + col * 8 + 4);
        float bb = b1[col];
        #pragma unroll
        for (int r = 0; r < 8; ++r) {
            int e = wv * 8 + r;
            const float4* efp = (const float4*)ef_s[e];
            float4 f0 = efp[0], f1 = efp[1];
            float s = bb + f0.x * w1a.x + f0.y * w1a.y + f0.z * w1a.z + f0.w * w1a.w
                        + f1.x * w1b.x + f1.y * w1b.y + f1.z * w1b.z + f1.w * w1b.w;
            ha[e][col] = silu_f(s);
        }
    }
    __syncthreads();
    // ---- layer2: 64 -> 64 (i-outer: one weight float4 load feeds 8 edges) ----
    {
        float accr[8];
        float bb = b2[col];
        #pragma unroll
        for (int r = 0; r < 8; ++r) accr[r] = bb;
        #pragma unroll
        for (int i = 0; i < 16; ++i) {
            float4 w = *(const float4*)(W2T + col * 64 + i * 4);
            #pragma unroll
            for (int r = 0; r < 8; ++r) {
                float4 h4 = *(const float4*)&ha[wv * 8 + r][i * 4];
                accr[r] += h4.x * w.x + h4.y * w.y + h4.z * w.z + h4.w * w.w;
            }
        }
        #pragma unroll
        for (int r = 0; r < 8; ++r) hb[wv * 8 + r][col] = silu_f(accr[r]);
    }
    __syncthreads();
    // ---- layer3: 64 -> 64 ----
    {
        float accr[8];
        float bb = b3[col];
        #pragma unroll
        for (int r = 0; r < 8; ++r) accr[r] = bb;
        #pragma unroll
        for (int i = 0; i < 16; ++i) {
            float4 w = *(const float4*)(W3T + col * 64 + i * 4);
            #pragma unroll
            for (int r = 0; r < 8; ++r) {
                float4 h4 = *(const float4*)&hb[wv * 8 + r][i * 4];
                accr[r] += h4.x * w.x + h4.y * w.y + h4.z * w.z + h4.w * w.w;
            }
        }
        #pragma unroll
        for (int r = 0; r < 8; ++r) ha[wv * 8 + r][col] = silu_f(accr[r]);
    }
    __syncthreads();
    // ---- split H -> bf16 hi/lo MFMA B-frags ----
    {
        int i0 = t * 8;
        int e = i0 >> 6, k = i0 & 63;
        const float* hp = &ha[e][k];
        u16x8 vh, vl;
        #pragma unroll
        for (int r = 0; r < 8; ++r) {
            float v = hp[r];
            unsigned h = bf16_rne(v);
            float fh = __uint_as_float(h << 16);
            unsigned lo = bf16_rne(v - fh);
            vh[r] = (u16)h;
            vl[r] = (u16)lo;
        }
        *(u16x8*)&HFh[e * 72 + k] = vh;
        *(u16x8*)&HFl[e * 72 + k] = vl;
    }
    __syncthreads();
    // ---- GEMM + fused bias + x epilogue -> A[p] ----
    int lane = t & 63;
    int eloc = lane & 15, kq = lane >> 4;
    int ntile = wv & 1, mhalf = wv >> 1;
    int e = ntile * 16 + eloc;
    const u16* hfh = &HFh[e * 72 + kq * 8];
    const u16* hfl = &HFl[e * 72 + kq * 8];
    bf16x8 bH0 = *(const bf16x8*)hfh;
    bf16x8 bH1 = *(const bf16x8*)(hfh + 32);
    bf16x8 bL0 = *(const bf16x8*)hfl;
    bf16x8 bL1 = *(const bf16x8*)(hfl + 32);
    const float* xrow = x + (size_t)srcs[e] * 128;
    float* arow = A + (size_t)(e0 + e) * 512;
    #pragma unroll 2
    for (int mt = 0; mt < 16; ++mt) {
        int m0 = mhalf * 256 + mt * 16;
        const u16* ap  = W4Th + (m0 + eloc) * 64 + kq * 8;
        const u16* apl = W4Tl + (m0 + eloc) * 64 + kq * 8;
        bf16x8 aH0 = *(const bf16x8*)ap;
        bf16x8 aH1 = *(const bf16x8*)(ap + 32);
        bf16x8 aL0 = *(const bf16x8*)apl;
        bf16x8 aL1 = *(const bf16x8*)(apl + 32);
        f32x4 a4 = (f32x4){0.f, 0.f, 0.f, 0.f};
        a4 = __builtin_amdgcn_mfma_f32_16x16x32_bf16(aH0, bH0, a4, 0, 0, 0);
        a4 = __builtin_amdgcn_mfma_f32_16x16x32_bf16(aH1, bH1, a4, 0, 0, 0);
        a4 = __builtin_amdgcn_mfma_f32_16x16x32_bf16(aH0, bL0, a4, 0, 0, 0);
        a4 = __builtin_amdgcn_mfma_f32_16x16x32_bf16(aH1, bL1, a4, 0, 0, 0);
        a4 = __builtin_amdgcn_mfma_f32_16x16x32_bf16(aL0, bH0, a4, 0, 0, 0);
        a4 = __builtin_amdgcn_mfma_f32_16x16x32_bf16(aL1, bH1, a4, 0, 0, 0);
        int c0 = m0 + kq * 4;                 // D row = kq*4 + reg
        float4 b4v4 = *(const float4*)(b4 + c0);
        float4 xv = *(const float4*)(xrow + (c0 & 127));
        float4 o;
        o.x = (a4[0] + b4v4.x) * xv.x;
        o.y = (a4[1] + b4v4.y) * xv.y;
        o.z = (a4[2] + b4v4.z) * xv.z;
        o.w = (a4[3] + b4v4.w) * xv.w;
        *(float4*)(arow + c0) = o;
    }
}

// ---------------- gather + contraction: 2 same-z nodes; A reads are LINEAR streams ----------------
__global__ __launch_bounds__(256) void k_gather2(const float* __restrict__ A,
                                                 const float* __restrict__ ea,
                                                 const float* __restrict__ C,
                                                 const int* __restrict__ row_start,
                                                 const int* __restrict__ elist,
                                                 const int* __restrict__ zrs,
                                                 const int* __restrict__ znodes,
                                                 float* __restrict__ out) {
    int z = blockIdx.x / NT2;
    int tile = blockIdx.x % NT2;
    int base = zrs[z], cz = zrs[z + 1] - base;
    int p0 = tile * 2;
    if (p0 >= cz) return;

    __shared__ float msgs_s[2][128 * 20];   // 20.5 KB
    __shared__ float Ys[GCAP2][16];         // 6 KB
    __shared__ int el_s[GCAP2];
    __shared__ int off_s[3];
    __shared__ int rb_s[2];
    __shared__ int nid_s[2];

    int t = threadIdx.x;
    if (t < 2) {
        int nid = (p0 + t < cz) ? znodes[base + p0 + t] : -1;
        nid_s[t] = nid;
        rb_s[t] = (nid >= 0) ? row_start[nid] : 0;
    }
    __syncthreads();
    if (t == 0) {
        int run = 0;
        for (int j = 0; j < 2; ++j) {
            off_s[j] = run;
            int nid = nid_s[j];
            int cnt = (nid >= 0) ? (row_start[nid + 1] - rb_s[j]) : 0;
            run += cnt;
            if (run > GCAP2) run = GCAP2;
        }
        off_s[2] = run;
    }
    __syncthreads();
    for (int j = 0; j < 2; ++j) {
        int a0 = off_s[j], a1 = off_s[j + 1];
        for (int i = a0 + t; i < a1; i += 256) el_s[i] = elist[rb_s[j] + (i - a0)];
    }
    __syncthreads();
    {   // stage Y (edge ids already canonical/sorted)
        int kk = off_s[2];
        for (int idx = t; idx < kk * 16; idx += 256) {
            int i = idx >> 4, d = idx & 15;
            Ys[i][d] = ea[(size_t)el_s[i] * 16 + d];
        }
    }
    __syncthreads();

    int mc = t & 127, hi = t >> 7;
    // ---- phase 1: per-node segment-sum; A rows contiguous (elist-position order) ----
    for (int j = 0; j < 2; ++j) {
        float acc[8];
        #pragma unroll
        for (int q = 0; q < 8; ++q) acc[q] = 0.f;
        int a0 = off_s[j], a1 = off_s[j + 1];
        const float* Ab = A + (size_t)rb_s[j] * 512;
        for (int p = a0; p < a1; ++p) {
            const float* Ae = Ab + (size_t)(p - a0) * 512;
            const float* Yp = &Ys[p][hi * 8];
            float y[8];
            #pragma unroll
            for (int q = 0; q < 8; ++q) y[q] = Yp[q];
            if (hi == 0) {
                float a0v = Ae[mc], a1v = Ae[128 + mc], a2v = Ae[256 + mc];
                acc[0] += a0v * y[0];
                acc[1] += a1v * y[1]; acc[2] += a1v * y[2]; acc[3] += a1v * y[3];
                acc[4] += a2v * y[4]; acc[5] += a2v * y[5]; acc[6] += a2v * y[6]; acc[7] += a2v * y[7];
            } else {
                float a2v = Ae[256 + mc], a3v = Ae[384 + mc];
                acc[0] += a2v * y[0];
                #pragma unroll
                for (int q = 1; q < 8; ++q) acc[q] += a3v * y[q];
            }
        }
        float* mrow = &msgs_s[j][mc * 20 + hi * 8];
        #pragma unroll
        for (int q = 0; q < 8; ++q) mrow[q] = acc[q];
    }
    __syncthreads();

    // ---- phase 2: contraction, C amortized over 2 nodes ----
    float o[2][8];
    #pragma unroll
    for (int j = 0; j < 2; ++j)
        #pragma unroll
        for (int q = 0; q < 8; ++q) o[j][q] = 0.f;
    if (hi == 0) {
        const float* C0 = C + (size_t)(0 * 10 + z) * 16384 + mc;
        const float* C1 = C + (size_t)(1 * 10 + z) * 16384 + mc;
        const float* C2 = C + (size_t)(2 * 10 + z) * 16384 + mc;
        for (int u = 0; u < 128; ++u) {
            float c0 = C0[u * 128], c1 = C1[u * 128], c2 = C2[u * 128];
            #pragma unroll
            for (int j = 0; j < 2; ++j) {
                const float4* mp = (const float4*)&msgs_s[j][u * 20];
                float4 m0 = mp[0], m1 = mp[1];
                o[j][0] += m0.x * c0;
                o[j][1] += m0.y * c1; o[j][2] += m0.z * c1; o[j][3] += m0.w * c1;
                o[j][4] += m1.x * c2; o[j][5] += m1.y * c2; o[j][6] += m1.z * c2; o[j][7] += m1.w * c2;
            }
        }
    } else {
        const float* C2 = C + (size_t)(2 * 10 + z) * 16384 + mc;
        const float* C3 = C + (size_t)(3 * 10 + z) * 16384 + mc;
        for (int u = 0; u < 128; ++u) {
            float c2 = C2[u * 128], c3 = C3[u * 128];
            #pragma unroll
            for (int j = 0; j < 2; ++j) {
                const float4* mp = (const float4*)&msgs_s[j][u * 20 + 8];
                float4 m0 = mp[0], m1 = mp[1];
                o[j][0] += m0.x * c2;
                o[j][1] += m0.y * c3; o[j][2] += m0.z * c3; o[j][3] += m0.w * c3;
                o[j][4] += m1.x * c3; o[j][5] += m1.y * c3; o[j][6] += m1.z * c3; o[j][7] += m1.w * c3;
            }
        }
    }
    #pragma unroll
    for (int j = 0; j < 2; ++j) {
        int nid = nid_s[j];
        if (nid < 0) continue;
        float4 v0 = make_float4(o[j][0], o[j][1], o[j][2], o[j][3]);
        float4 v1 = make_float4(o[j][4], o[j][5], o[j][6], o[j][7]);
        float4* dst = (float4*)(out + (size_t)nid * 2048 + mc * 16 + hi * 8);
        dst[0] = v0;
        dst[1] = v1;
    }
}

extern "C" void kernel_launch(void* const* d_in, const int* in_sizes, int n_in,
                              void* d_out, int out_size, void* d_ws, size_t ws_size,
                              hipStream_t stream) {
    const float* na   = (const float*)d_in[0];
    const float* nf   = (const float*)d_in[1];
    const float* ea   = (const float*)d_in[2];
    const float* ef   = (const float*)d_in[3];
    const int*   eidx = (const int*)d_in[4];
    const float* Wup  = (const float*)d_in[5];
    const float* W1   = (const float*)d_in[6];
    const float* b1   = (const float*)d_in[7];
    const float* W2   = (const float*)d_in[8];
    const float* b2   = (const float*)d_in[9];
    const float* W3   = (const float*)d_in[10];
    const float* b3   = (const float*)d_in[11];
    const float* W4   = (const float*)d_in[12];
    const float* b4   = (const float*)d_in[13];
    const float* Wlin = (const float*)d_in[14];
    const float* Wskip= (const float*)d_in[15];
    float* out = (float*)d_out;

    char* ws = (char*)d_ws;
    float* A        = (float*)(ws + WS_A);
    float* x        = (float*)(ws + WS_X);
    float* C        = (float*)(ws + WS_C);
    int*   counts   = (int*)(ws + WS_COUNTS);   // becomes cursor after k_scan
    int*   zcnt     = (int*)(ws + WS_ZCNT);
    int*   rowstart = (int*)(ws + WS_ROWSTART);
    int*   zrs      = (int*)(ws + WS_ZRS);
    int*   zcur     = (int*)(ws + WS_ZCUR);
    int*   elist    = (int*)(ws + WS_ELIST);
    int*   znodes   = (int*)(ws + WS_ZNODES);

    // d_out scratch: prep weights (k_prep -> k_edge); fully overwritten by k_gather2
    float* W1T  = (float*)d_out;
    float* W2T  = W1T + 512;
    float* W3T  = W1T + 4608;
    u16*   W4Th = (u16*)((char*)d_out + 34816);
    u16*   W4Tl = (u16*)((char*)d_out + 100352);

    hipMemsetAsync(counts, 0, 32768 + 64, stream);  // counts + zcnt
    k_prep<<<128, 256, 0, stream>>>(W1, W2, W3, W4, W1T, W2T, W3T, W4Th, W4Tl);
    k_count<<<NE / 256, 256, 0, stream>>>(eidx, na, counts, zcnt);
    k_scan<<<1, 1024, 0, stream>>>(counts, rowstart, zcnt, zrs, zcur);
    k_scatter<<<NE / 256, 256, 0, stream>>>(eidx, na, counts, elist, zcur, znodes);
    k_sort<<<NN / 256, 256, 0, stream>>>(rowstart, elist);
    k_x<<<NN / 16, 256, 0, stream>>>(nf, Wup, x);
    k_C<<<320, 256, 0, stream>>>(Wlin, Wskip, C);
    k_edge<<<NE / 32, 256, 0, stream>>>(ef, eidx, elist, b1, b2, b3, b4,
                                        W1T, W2T, W3T, W4Th, W4Tl, x, A);
    k_gather2<<<10 * NT2, 256, 0, stream>>>(A, ea, C, rowstart, elist, zrs, znodes, out);
}

// Round 12
// 324.599 us; speedup vs baseline: 1.2773x; 1.0409x over previous
//
#include <hip/hip_runtime.h>
#include <math.h>

#define NE 65536
#define NN 8192
#define NT2 480      // 2-node tiles per z
#define GCAP2 96     // max edges per 2-node block (mean 16)
#define SCAP 3072    // k_sort staging
#define EPB 64       // edges per k_edgew block (16 per wave)

typedef unsigned short u16;
typedef float f32x4 __attribute__((ext_vector_type(4)));
typedef __bf16 bf16x8 __attribute__((ext_vector_type(8)));
typedef unsigned short u16x8 __attribute__((ext_vector_type(8)));

// ---- ws layout (bytes); total within 141,394,072 (proven safe R1-R9) ----
#define WS_A        0u           // 134,217,728: A[p][512] f32, p = elist position
#define WS_X        134217728u   // 4,194,304
#define WS_C        138412032u   // 2,621,440  C f32 [lz=40][u=128][u2=128]
#define WS_COUNTS   141033472u   // 32,768
#define WS_ZCNT     141066240u   // 64
#define WS_ROWSTART 141066304u   // 32,772
#define WS_ZRS      141099076u   // 44
#define WS_ZCUR     141099120u   // 40
#define WS_ELIST    141099160u   // 262,144
#define WS_ZNODES   141361304u   // 32,768 -> end 141,394,072

__device__ __forceinline__ unsigned bf16_rne(float v) {
    unsigned u = __float_as_uint(v);
    return (u + 0x7FFFu + ((u >> 16) & 1u)) >> 16;
}

__device__ __forceinline__ float silu_f(float s) {
    return s * __builtin_amdgcn_rcpf(1.f + __expf(-s));   // validated R6-R9
}

// ---------------- CSR build (edge by dst) + z-grouping of nodes ----------------
__global__ void k_count(const int* __restrict__ eidx, const float* __restrict__ na,
                        int* __restrict__ counts, int* __restrict__ zcnt) {
    int e = blockIdx.x * 256 + threadIdx.x;
    if (e < NE) atomicAdd(&counts[eidx[NE + e]], 1);
    if (e < NN) {
        const float* row = na + (size_t)e * 10;
        int z = 0;
        #pragma unroll
        for (int w = 1; w < 10; ++w) if (row[w] > 0.5f) z = w;
        atomicAdd(&zcnt[z], 1);
    }
}

__global__ __launch_bounds__(1024) void k_scan(int* __restrict__ counts,
                                               int* __restrict__ row_start,
                                               const int* __restrict__ zcnt,
                                               int* __restrict__ zrs, int* __restrict__ zcur) {
    __shared__ int sd[1024];
    int t = threadIdx.x;
    int c[8];
    int s = 0;
    #pragma unroll
    for (int i = 0; i < 8; ++i) { c[i] = counts[t * 8 + i]; s += c[i]; }
    sd[t] = s;
    __syncthreads();
    for (int off = 1; off < 1024; off <<= 1) {
        int v = (t >= off) ? sd[t - off] : 0;
        __syncthreads();
        sd[t] += v;
        __syncthreads();
    }
    int run = (t == 0) ? 0 : sd[t - 1];
    #pragma unroll
    for (int i = 0; i < 8; ++i) {
        row_start[t * 8 + i] = run;
        counts[t * 8 + i] = run;   // cursor
        run += c[i];
    }
    if (t == 1023) row_start[8192] = run;
    if (t == 0) {
        int zr = 0;
        for (int i = 0; i < 10; ++i) { zrs[i] = zr; zcur[i] = zr; zr += zcnt[i]; }
        zrs[10] = zr;
    }
}

__global__ void k_scatter(const int* __restrict__ eidx, const float* __restrict__ na,
                          int* __restrict__ cursor, int* __restrict__ elist,
                          int* __restrict__ zcur, int* __restrict__ znodes) {
    int e = blockIdx.x * 256 + threadIdx.x;
    if (e < NE) {
        int p = atomicAdd(&cursor[eidx[NE + e]], 1);
        elist[p] = e;
    }
    if (e < NN) {
        const float* row = na + (size_t)e * 10;
        int z = 0;
        #pragma unroll
        for (int w = 1; w < 10; ++w) if (row[w] > 0.5f) z = w;
        int p = atomicAdd(&zcur[z], 1);
        znodes[p] = e;
    }
}

// ---------------- canonicalize elist: per-node ascending sort (determinism) ----------------
__global__ __launch_bounds__(256) void k_sort(const int* __restrict__ row_start,
                                              int* __restrict__ elist) {
    __shared__ int buf[SCAP];
    int n0 = blockIdx.x * 256;
    int t = threadIdx.x;
    int r0 = row_start[n0], r1 = row_start[n0 + 256];
    int len = r1 - r0;
    if (len <= SCAP) {
        for (int i = t; i < len; i += 256) buf[i] = elist[r0 + i];
        __syncthreads();
        int a0 = row_start[n0 + t] - r0, a1 = row_start[n0 + t + 1] - r0;
        for (int i = a0 + 1; i < a1; ++i) {
            int key = buf[i]; int j = i - 1;
            while (j >= a0 && buf[j] > key) { buf[j + 1] = buf[j]; --j; }
            buf[j + 1] = key;
        }
        __syncthreads();
        for (int i = t; i < len; i += 256) elist[r0 + i] = buf[i];
    } else {
        int a0 = row_start[n0 + t], a1 = row_start[n0 + t + 1];
        for (int i = a0 + 1; i < a1; ++i) {
            int key = elist[i]; int j = i - 1;
            while (j >= a0 && elist[j] > key) { elist[j + 1] = elist[j]; --j; }
            elist[j + 1] = key;
        }
    }
}

// ---------------- weight prep -> d_out scratch ----------------
__global__ __launch_bounds__(256) void k_prep(const float* __restrict__ W1, const float* __restrict__ W2,
                                              const float* __restrict__ W3, const float* __restrict__ W4,
                                              float* __restrict__ W1T, float* __restrict__ W2T,
                                              float* __restrict__ W3T, u16* __restrict__ W4Th,
                                              u16* __restrict__ W4Tl) {
    int t = blockIdx.x * 256 + threadIdx.x;
    if (t < 512) { int c = t >> 3, k = t & 7; W1T[t] = W1[k * 64 + c]; }
    if (t < 4096) {
        int c = t >> 6, k = t & 63;
        W2T[t] = W2[k * 64 + c];
        W3T[t] = W3[k * 64 + c];
    }
    if (t < 32768) {
        int c = t >> 6, k = t & 63;
        float v = W4[k * 512 + c];
        unsigned h = bf16_rne(v);
        float fh = __uint_as_float(h << 16);
        unsigned lo = bf16_rne(v - fh);
        W4Th[t] = (u16)h;
        W4Tl[t] = (u16)lo;
    }
}

// ---------------- x = node_feats @ W_up / sqrt(128) ----------------
__global__ __launch_bounds__(256) void k_x(const float* __restrict__ nf,
                                           const float* __restrict__ Wup,
                                           float* __restrict__ x) {
    __shared__ float nf_s[16][128];
    int n0 = blockIdx.x * 16;
    int t = threadIdx.x;
    for (int i = t; i < 16 * 128; i += 256) nf_s[i >> 7][i & 127] = nf[n0 * 128 + i];
    __syncthreads();
    int mc = t & 127, half = t >> 7;
    float acc[8];
    #pragma unroll
    for (int j = 0; j < 8; ++j) acc[j] = 0.f;
    for (int k = 0; k < 128; ++k) {
        float w = Wup[k * 128 + mc];
        #pragma unroll
        for (int j = 0; j < 8; ++j) acc[j] += nf_s[half * 8 + j][k] * w;
    }
    const float rs = 0.08838834764831845f;  // 1/sqrt(128)
    #pragma unroll
    for (int j = 0; j < 8; ++j) x[(n0 + half * 8 + j) * 128 + mc] = acc[j] * rs;
}

// ---------------- C[lz][u][u2] f32 ----------------
__global__ __launch_bounds__(256) void k_C(const float* __restrict__ Wlin,
                                           const float* __restrict__ Wskip,
                                           float* __restrict__ C) {
    __shared__ float wl_s[16][128];
    int b = blockIdx.x;
    int lz = b >> 3, ut = b & 7;
    int l = lz / 10, z = lz % 10;
    int t = threadIdx.x;
    for (int i = t; i < 16 * 128; i += 256) {
        int u = i >> 7, v = i & 127;
        wl_s[u][v] = Wlin[(l * 128 + ut * 16 + u) * 128 + v];
    }
    __syncthreads();
    int u2 = t & 127, uh = t >> 7;
    float acc[8];
    #pragma unroll
    for (int r = 0; r < 8; ++r) acc[r] = 0.f;
    const float* Wsk = Wskip + ((size_t)l * 128 * 10 + z) * 128 + u2;  // stride over v: 1280
    for (int v = 0; v < 128; v += 4) {
        float s0 = Wsk[(size_t)(v + 0) * 1280];
        float s1 = Wsk[(size_t)(v + 1) * 1280];
        float s2 = Wsk[(size_t)(v + 2) * 1280];
        float s3 = Wsk[(size_t)(v + 3) * 1280];
        #pragma unroll
        for (int r = 0; r < 8; ++r) {
            int u = uh * 8 + r;
            acc[r] += wl_s[u][v] * s0 + wl_s[u][v + 1] * s1
                    + wl_s[u][v + 2] * s2 + wl_s[u][v + 3] * s3;
        }
    }
    const float scale = 3.0881618e-04f;  // (1/sqrt(128)/8) * (1/sqrt(1280))
    #pragma unroll
    for (int r = 0; r < 8; ++r) {
        int u = ut * 16 + uh * 8 + r;
        C[((size_t)(l * 10 + z) * 128 + u) * 128 + u2] = acc[r] * scale;
    }
}

// ---------------- BARRIER-FREE edge kernel: one wave owns 16 edges end-to-end ----------------
// Wave-private LDS arenas; zero __syncthreads (intra-wave LDS ordering via in-order DS pipe).
__global__ __launch_bounds__(256, 4) void k_edgew(const float* __restrict__ ef,
                                                  const int* __restrict__ eidx,
                                                  const int* __restrict__ elist,
                                                  const float* __restrict__ b1, const float* __restrict__ b2,
                                                  const float* __restrict__ b3, const float* __restrict__ b4,
                                                  const float* __restrict__ W1T, const float* __restrict__ W2T,
                                                  const float* __restrict__ W3T,
                                                  const u16* __restrict__ W4Th, const u16* __restrict__ W4Tl,
                                                  const float* __restrict__ x,
                                                  float* __restrict__ A) {
    __shared__ float ha_s[4][16 * 68];      // 4 x 4352 B
    __shared__ float hb_s[4][1156];         // 4 x 4624 B arena: hb f32 [16][68], then HFh/HFl overlay
    __shared__ float ef_s[4][16][8];
    __shared__ int   eid_s[4][16];
    __shared__ int   src_s[4][16];

    int t = threadIdx.x;
    int wv = t >> 6, lane = t & 63;
    int p0 = blockIdx.x * EPB + wv * 16;    // this wave's elist-position base

    if (lane < 16) {
        int eid = elist[p0 + lane];
        eid_s[wv][lane] = eid;
        src_s[wv][lane] = eidx[eid];
    }
    {   // stage edge features (wave-private)
        int i1 = lane;
        int e = i1 >> 3, d = i1 & 7;
        ef_s[wv][e][d] = ef[(size_t)eid_s[wv][e] * 8 + d];
        int i2 = lane + 64;
        e = i2 >> 3; d = i2 & 7;
        ef_s[wv][e][d] = ef[(size_t)eid_s[wv][e] * 8 + d];
    }
    int col = lane;                          // 64 lanes = 64 MLP columns
    float* ha = &ha_s[wv][0];                // stride 68
    float* hb = &hb_s[wv][0];                // stride 68 (first 4352 B of arena)
    // ---- layer1: 8 -> 64 ----
    {
        float4 w1a = *(const float4*)(W1T + col * 8);
        float4 w1b = *(const float4*)(W1T + col * 8 + 4);
        float bb = b1[col];
        #pragma unroll
        for (int e = 0; e < 16; ++e) {
            const float4* efp = (const float4*)&ef_s[wv][e][0];
            float4 f0 = efp[0], f1 = efp[1];
            float s = bb + f0.x * w1a.x + f0.y * w1a.y + f0.z * w1a.z + f0.w * w1a.w
                        + f1.x * w1b.x + f1.y * w1b.y + f1.z * w1b.z + f1.w * w1b.w;
            ha[e * 68 + col] = silu_f(s);
        }
    }
    // ---- layer2: 64 -> 64 (i-outer; ha reads are wave-uniform broadcasts) ----
    {
        float acc[16];
        float bb = b2[col];
        #pragma unroll
        for (int e = 0; e < 16; ++e) acc[e] = bb;
        #pragma unroll
        for (int i = 0; i < 16; ++i) {
            float4 w = *(const float4*)(W2T + col * 64 + i * 4);
            #pragma unroll
            for (int e = 0; e < 16; ++e) {
                float4 h4 = *(const float4*)&ha[e * 68 + i * 4];
                acc[e] += h4.x * w.x + h4.y * w.y + h4.z * w.z + h4.w * w.w;
            }
        }
        #pragma unroll
        for (int e = 0; e < 16; ++e) hb[e * 68 + col] = silu_f(acc[e]);
    }
    // ---- layer3: 64 -> 64 (hb -> ha) ----
    {
        float acc[16];
        float bb = b3[col];
        #pragma unroll
        for (int e = 0; e < 16; ++e) acc[e] = bb;
        #pragma unroll
        for (int i = 0; i < 16; ++i) {
            float4 w = *(const float4*)(W3T + col * 64 + i * 4);
            #pragma unroll
            for (int e = 0; e < 16; ++e) {
                float4 h4 = *(const float4*)&hb[e * 68 + i * 4];
                acc[e] += h4.x * w.x + h4.y * w.y + h4.z * w.z + h4.w * w.w;
            }
        }
        #pragma unroll
        for (int e = 0; e < 16; ++e) ha[e * 68 + col] = silu_f(acc[e]);
    }
    // ---- split H (ha) -> bf16 hi/lo frags, overlaying the hb arena ----
    u16* HFh = (u16*)hb;            // [16][72] u16 = 2304 B
    u16* HFl = ((u16*)hb) + 1152;   // next 2304 B
    {
        int e = lane >> 2, k0 = (lane & 3) * 16;
        const float* hp = &ha[e * 68 + k0];
        u16x8 vh0, vl0, vh1, vl1;
        #pragma unroll
        for (int r = 0; r < 8; ++r) {
            float v = hp[r];
            unsigned h = bf16_rne(v);
            float fh = __uint_as_float(h << 16);
            unsigned lo = bf16_rne(v - fh);
            vh0[r] = (u16)h; vl0[r] = (u16)lo;
        }
        #pragma unroll
        for (int r = 0; r < 8; ++r) {
            float v = hp[8 + r];
            unsigned h = bf16_rne(v);
            float fh = __uint_as_float(h << 16);
            unsigned lo = bf16_rne(v - fh);
            vh1[r] = (u16)h; vl1[r] = (u16)lo;
        }
        *(u16x8*)&HFh[e * 72 + k0]     = vh0;
        *(u16x8*)&HFh[e * 72 + k0 + 8] = vh1;
        *(u16x8*)&HFl[e * 72 + k0]     = vl0;
        *(u16x8*)&HFl[e * 72 + k0 + 8] = vl1;
    }
    // ---- GEMM: 512m x 16e per wave, split-bf16 MFMA; fused bias + x epilogue ----
    int eloc = lane & 15, kq = lane >> 4;
    const u16* hfh = &HFh[eloc * 72 + kq * 8];
    const u16* hfl = &HFl[eloc * 72 + kq * 8];
    bf16x8 bH0 = *(const bf16x8*)hfh;
    bf16x8 bH1 = *(const bf16x8*)(hfh + 32);
    bf16x8 bL0 = *(const bf16x8*)hfl;
    bf16x8 bL1 = *(const bf16x8*)(hfl + 32);
    const float* xrow = x + (size_t)src_s[wv][eloc] * 128;
    float* arow = A + (size_t)(p0 + eloc) * 512;
    #pragma unroll 4
    for (int mt = 0; mt < 32; ++mt) {
        int m0 = mt * 16;
        const u16* ap  = W4Th + (m0 + eloc) * 64 + kq * 8;
        const u16* apl = W4Tl + (m0 + eloc) * 64 + kq * 8;
        bf16x8 aH0 = *(const bf16x8*)ap;
        bf16x8 aH1 = *(const bf16x8*)(ap + 32);
        bf16x8 aL0 = *(const bf16x8*)apl;
        bf16x8 aL1 = *(const bf16x8*)(apl + 32);
        f32x4 a4 = (f32x4){0.f, 0.f, 0.f, 0.f};
        a4 = __builtin_amdgcn_mfma_f32_16x16x32_bf16(aH0, bH0, a4, 0, 0, 0);
        a4 = __builtin_amdgcn_mfma_f32_16x16x32_bf16(aH1, bH1, a4, 0, 0, 0);
        a4 = __builtin_amdgcn_mfma_f32_16x16x32_bf16(aH0, bL0, a4, 0, 0, 0);
        a4 = __builtin_amdgcn_mfma_f32_16x16x32_bf16(aH1, bL1, a4, 0, 0, 0);
        a4 = __builtin_amdgcn_mfma_f32_16x16x32_bf16(aL0, bH0, a4, 0, 0, 0);
        a4 = __builtin_amdgcn_mfma_f32_16x16x32_bf16(aL1, bH1, a4, 0, 0, 0);
        int c0 = m0 + kq * 4;                 // D row = kq*4 + reg (verified R5-R9)
        float4 b4v4 = *(const float4*)(b4 + c0);
        float4 xv = *(const float4*)(xrow + (c0 & 127));
        float4 o;
        o.x = (a4[0] + b4v4.x) * xv.x;
        o.y = (a4[1] + b4v4.y) * xv.y;
        o.z = (a4[2] + b4v4.z) * xv.z;
        o.w = (a4[3] + b4v4.w) * xv.w;
        *(float4*)(arow + c0) = o;
    }
}

// ---------------- gather + contraction: 2 same-z nodes; A reads are linear streams ----------------
__global__ __launch_bounds__(256) void k_gather2(const float* __restrict__ A,
                                                 const float* __restrict__ ea,
                                                 const float* __restrict__ C,
                                                 const int* __restrict__ row_start,
                                                 const int* __restrict__ elist,
                                                 const int* __restrict__ zrs,
                                                 const int* __restrict__ znodes,
                                                 float* __restrict__ out) {
    int z = blockIdx.x / NT2;
    int tile = blockIdx.x % NT2;
    int base = zrs[z], cz = zrs[z + 1] - base;
    int p0 = tile * 2;
    if (p0 >= cz) return;

    __shared__ float msgs_s[2][128 * 20];
    __shared__ float Ys[GCAP2][16];
    __shared__ int el_s[GCAP2];
    __shared__ int off_s[3];
    __shared__ int rb_s[2];
    __shared__ int nid_s[2];

    int t = threadIdx.x;
    if (t < 2) {
        int nid = (p0 + t < cz) ? znodes[base + p0 + t] : -1;
        nid_s[t] = nid;
        rb_s[t] = (nid >= 0) ? row_start[nid] : 0;
    }
    __syncthreads();
    if (t == 0) {
        int run = 0;
        for (int j = 0; j < 2; ++j) {
            off_s[j] = run;
            int nid = nid_s[j];
            int cnt = (nid >= 0) ? (row_start[nid + 1] - rb_s[j]) : 0;
            run += cnt;
            if (run > GCAP2) run = GCAP2;
        }
        off_s[2] = run;
    }
    __syncthreads();
    for (int j = 0; j < 2; ++j) {
        int a0 = off_s[j], a1 = off_s[j + 1];
        for (int i = a0 + t; i < a1; i += 256) el_s[i] = elist[rb_s[j] + (i - a0)];
    }
    __syncthreads();
    {
        int kk = off_s[2];
        for (int idx = t; idx < kk * 16; idx += 256) {
            int i = idx >> 4, d = idx & 15;
            Ys[i][d] = ea[(size_t)el_s[i] * 16 + d];
        }
    }
    __syncthreads();

    int mc = t & 127, hi = t >> 7;
    for (int j = 0; j < 2; ++j) {
        float acc[8];
        #pragma unroll
        for (int q = 0; q < 8; ++q) acc[q] = 0.f;
        int a0 = off_s[j], a1 = off_s[j + 1];
        const float* Ab = A + (size_t)rb_s[j] * 512;
        for (int p = a0; p < a1; ++p) {
            const float* Ae = Ab + (size_t)(p - a0) * 512;
            const float* Yp = &Ys[p][hi * 8];
            float y[8];
            #pragma unroll
            for (int q = 0; q < 8; ++q) y[q] = Yp[q];
            if (hi == 0) {
                float a0v = Ae[mc], a1v = Ae[128 + mc], a2v = Ae[256 + mc];
                acc[0] += a0v * y[0];
                acc[1] += a1v * y[1]; acc[2] += a1v * y[2]; acc[3] += a1v * y[3];
                acc[4] += a2v * y[4]; acc[5] += a2v * y[5]; acc[6] += a2v * y[6]; acc[7] += a2v * y[7];
            } else {
                float a2v = Ae[256 + mc], a3v = Ae[384 + mc];
                acc[0] += a2v * y[0];
                #pragma unroll
                for (int q = 1; q < 8; ++q) acc[q] += a3v * y[q];
            }
        }
        float* mrow = &msgs_s[j][mc * 20 + hi * 8];
        #pragma unroll
        for (int q = 0; q < 8; ++q) mrow[q] = acc[q];
    }
    __syncthreads();

    float o[2][8];
    #pragma unroll
    for (int j = 0; j < 2; ++j)
        #pragma unroll
        for (int q = 0; q < 8; ++q) o[j][q] = 0.f;
    if (hi == 0) {
        const float* C0 = C + (size_t)(0 * 10 + z) * 16384 + mc;
        const float* C1 = C + (size_t)(1 * 10 + z) * 16384 + mc;
        const float* C2 = C + (size_t)(2 * 10 + z) * 16384 + mc;
        for (int u = 0; u < 128; ++u) {
            float c0 = C0[u * 128], c1 = C1[u * 128], c2 = C2[u * 128];
            #pragma unroll
            for (int j = 0; j < 2; ++j) {
                const float4* mp = (const float4*)&msgs_s[j][u * 20];
                float4 m0 = mp[0], m1 = mp[1];
                o[j][0] += m0.x * c0;
                o[j][1] += m0.y * c1; o[j][2] += m0.z * c1; o[j][3] += m0.w * c1;
                o[j][4] += m1.x * c2; o[j][5] += m1.y * c2; o[j][6] += m1.z * c2; o[j][7] += m1.w * c2;
            }
        }
    } else {
        const float* C2 = C + (size_t)(2 * 10 + z) * 16384 + mc;
        const float* C3 = C + (size_t)(3 * 10 + z) * 16384 + mc;
        for (int u = 0; u < 128; ++u) {
            float c2 = C2[u * 128], c3 = C3[u * 128];
            #pragma unroll
            for (int j = 0; j < 2; ++j) {
                const float4* mp = (const float4*)&msgs_s[j][u * 20 + 8];
                float4 m0 = mp[0], m1 = mp[1];
                o[j][0] += m0.x * c2;
                o[j][1] += m0.y * c3; o[j][2] += m0.z * c3; o[j][3] += m0.w * c3;
                o[j][4] += m1.x * c3; o[j][5] += m1.y * c3; o[j][6] += m1.z * c3; o[j][7] += m1.w * c3;
            }
        }
    }
    #pragma unroll
    for (int j = 0; j < 2; ++j) {
        int nid = nid_s[j];
        if (nid < 0) continue;
        float4 v0 = make_float4(o[j][0], o[j][1], o[j][2], o[j][3]);
        float4 v1 = make_float4(o[j][4], o[j][5], o[j][6], o[j][7]);
        float4* dst = (float4*)(out + (size_t)nid * 2048 + mc * 16 + hi * 8);
        dst[0] = v0;
        dst[1] = v1;
    }
}

extern "C" void kernel_launch(void* const* d_in, const int* in_sizes, int n_in,
                              void* d_out, int out_size, void* d_ws, size_t ws_size,
                              hipStream_t stream) {
    const float* na   = (const float*)d_in[0];
    const float* nf   = (const float*)d_in[1];
    const float* ea   = (const float*)d_in[2];
    const float* ef   = (const float*)d_in[3];
    const int*   eidx = (const int*)d_in[4];
    const float* Wup  = (const float*)d_in[5];
    const float* W1   = (const float*)d_in[6];
    const float* b1   = (const float*)d_in[7];
    const float* W2   = (const float*)d_in[8];
    const float* b2   = (const float*)d_in[9];
    const float* W3   = (const float*)d_in[10];
    const float* b3   = (const float*)d_in[11];
    const float* W4   = (const float*)d_in[12];
    const float* b4   = (const float*)d_in[13];
    const float* Wlin = (const float*)d_in[14];
    const float* Wskip= (const float*)d_in[15];
    float* out = (float*)d_out;

    char* ws = (char*)d_ws;
    float* A        = (float*)(ws + WS_A);
    float* x        = (float*)(ws + WS_X);
    float* C        = (float*)(ws + WS_C);
    int*   counts   = (int*)(ws + WS_COUNTS);
    int*   zcnt     = (int*)(ws + WS_ZCNT);
    int*   rowstart = (int*)(ws + WS_ROWSTART);
    int*   zrs      = (int*)(ws + WS_ZRS);
    int*   zcur     = (int*)(ws + WS_ZCUR);
    int*   elist    = (int*)(ws + WS_ELIST);
    int*   znodes   = (int*)(ws + WS_ZNODES);

    // d_out scratch: prep weights (k_prep -> k_edgew); fully overwritten by k_gather2
    float* W1T  = (float*)d_out;
    float* W2T  = W1T + 512;
    float* W3T  = W1T + 4608;
    u16*   W4Th = (u16*)((char*)d_out + 34816);
    u16*   W4Tl = (u16*)((char*)d_out + 100352);

    hipMemsetAsync(counts, 0, 32768 + 64, stream);  // counts + zcnt
    k_prep<<<128, 256, 0, stream>>>(W1, W2, W3, W4, W1T, W2T, W3T, W4Th, W4Tl);
    k_count<<<NE / 256, 256, 0, stream>>>(eidx, na, counts, zcnt);
    k_scan<<<1, 1024, 0, stream>>>(counts, rowstart, zcnt, zrs, zcur);
    k_scatter<<<NE / 256, 256, 0, stream>>>(eidx, na, counts, elist, zcur, znodes);
    k_sort<<<NN / 256, 256, 0, stream>>>(rowstart, elist);
    k_x<<<NN / 16, 256, 0, stream>>>(nf, Wup, x);
    k_C<<<320, 256, 0, stream>>>(Wlin, Wskip, C);
    k_edgew<<<NE / EPB, 256, 0, stream>>>(ef, eidx, elist, b1, b2, b3, b4,
                                          W1T, W2T, W3T, W4Th, W4Tl, x, A);
    k_gather2<<<10 * NT2, 256, 0, stream>>>(A, ea, C, rowstart, elist, zrs, znodes, out);
}

// Round 14
// 310.136 us; speedup vs baseline: 1.3368x; 1.0466x over previous
//
#include <hip/hip_runtime.h>
#include <math.h>

#define NE 65536
#define NN 8192
#define NT3 320      // 3-node tiles per z (320*3=960 >= max z-group ~900)
#define GCAP3 128    // max edges per 3-node block (mean 24)
#define SCAP 3072    // k_sort staging
#define EPB 64       // edges per k_edgew block (16 per wave)

typedef unsigned short u16;
typedef float f32x4 __attribute__((ext_vector_type(4)));
typedef __bf16 bf16x8 __attribute__((ext_vector_type(8)));
typedef unsigned short u16x8 __attribute__((ext_vector_type(8)));

// ---- ws layout (bytes); total within 141,394,072 (proven safe R1-R12) ----
#define WS_A        0u           // 134,217,728: A[p][512] f32, p = elist position
#define WS_X        134217728u   // 4,194,304
#define WS_C        138412032u   // 2,621,440  C f32 [lz=40][u=128][u2=128]
#define WS_COUNTS   141033472u   // 32,768
#define WS_ZCNT     141066240u   // 64
#define WS_ROWSTART 141066304u   // 32,772
#define WS_ZRS      141099076u   // 44
#define WS_ZCUR     141099120u   // 40
#define WS_ELIST    141099160u   // 262,144
#define WS_ZNODES   141361304u   // 32,768 -> end 141,394,072

__device__ __forceinline__ unsigned bf16_rne(float v) {
    unsigned u = __float_as_uint(v);
    return (u + 0x7FFFu + ((u >> 16) & 1u)) >> 16;
}

__device__ __forceinline__ float silu_f(float s) {
    return s * __builtin_amdgcn_rcpf(1.f + __expf(-s));   // validated R6-R12
}

// ---------------- FUSED FRONT: k_x(512) + k_C(320) + k_prep(128) + k_count(256) ----------------
// All four are independent (disjoint outputs); fusing fills the machine and cuts launches.
__global__ __launch_bounds__(256) void k_front(
    const float* __restrict__ nf, const float* __restrict__ Wup, float* __restrict__ x,
    const float* __restrict__ Wlin, const float* __restrict__ Wskip, float* __restrict__ C,
    const float* __restrict__ W1, const float* __restrict__ W2,
    const float* __restrict__ W3, const float* __restrict__ W4,
    float* __restrict__ W1T, float* __restrict__ W2T, float* __restrict__ W3T,
    u16* __restrict__ W4Th, u16* __restrict__ W4Tl,
    const int* __restrict__ eidx, const float* __restrict__ na,
    int* __restrict__ counts, int* __restrict__ zcnt)
{
    __shared__ float sh[16 * 128];
    int b = blockIdx.x;
    int t = threadIdx.x;
    if (b < 512) {
        // ---- k_x: x = nf @ W_up / sqrt(128), 16 nodes/block ----
        int n0 = b * 16;
        for (int i = t; i < 16 * 128; i += 256) sh[i] = nf[(size_t)n0 * 128 + i];
        __syncthreads();
        int mc = t & 127, half = t >> 7;
        float acc[8];
        #pragma unroll
        for (int j = 0; j < 8; ++j) acc[j] = 0.f;
        #pragma unroll 4
        for (int k = 0; k < 128; ++k) {
            float w = Wup[k * 128 + mc];
            #pragma unroll
            for (int j = 0; j < 8; ++j) acc[j] += sh[(half * 8 + j) * 128 + k] * w;
        }
        const float rs = 0.08838834764831845f;  // 1/sqrt(128)
        #pragma unroll
        for (int j = 0; j < 8; ++j) x[(size_t)(n0 + half * 8 + j) * 128 + mc] = acc[j] * rs;
    } else if (b < 832) {
        // ---- k_C: C[lz][u][u2] ----
        int b2 = b - 512;
        int lz = b2 >> 3, ut = b2 & 7;
        int l = lz / 10, z = lz % 10;
        for (int i = t; i < 16 * 128; i += 256) {
            int u = i >> 7, v = i & 127;
            sh[u * 128 + v] = Wlin[(l * 128 + ut * 16 + u) * 128 + v];
        }
        __syncthreads();
        int u2 = t & 127, uh = t >> 7;
        float acc[8];
        #pragma unroll
        for (int r = 0; r < 8; ++r) acc[r] = 0.f;
        const float* Wsk = Wskip + ((size_t)l * 128 * 10 + z) * 128 + u2;
        for (int v = 0; v < 128; v += 4) {
            float s0 = Wsk[(size_t)(v + 0) * 1280];
            float s1 = Wsk[(size_t)(v + 1) * 1280];
            float s2 = Wsk[(size_t)(v + 2) * 1280];
            float s3 = Wsk[(size_t)(v + 3) * 1280];
            #pragma unroll
            for (int r = 0; r < 8; ++r) {
                int u = uh * 8 + r;
                acc[r] += sh[u * 128 + v] * s0 + sh[u * 128 + v + 1] * s1
                        + sh[u * 128 + v + 2] * s2 + sh[u * 128 + v + 3] * s3;
            }
        }
        const float scale = 3.0881618e-04f;  // (1/sqrt(128)/8) * (1/sqrt(1280))
        #pragma unroll
        for (int r = 0; r < 8; ++r) {
            int u = ut * 16 + uh * 8 + r;
            C[((size_t)(l * 10 + z) * 128 + u) * 128 + u2] = acc[r] * scale;
        }
    } else if (b < 960) {
        // ---- k_prep: weight transposes + W4^T split-bf16 ----
        int tt = (b - 832) * 256 + t;
        if (tt < 512) { int c = tt >> 3, k = tt & 7; W1T[tt] = W1[k * 64 + c]; }
        if (tt < 4096) {
            int c = tt >> 6, k = tt & 63;
            W2T[tt] = W2[k * 64 + c];
            W3T[tt] = W3[k * 64 + c];
        }
        if (tt < 32768) {
            int c = tt >> 6, k = tt & 63;
            float v = W4[k * 512 + c];
            unsigned h = bf16_rne(v);
            float fh = __uint_as_float(h << 16);
            unsigned lo = bf16_rne(v - fh);
            W4Th[tt] = (u16)h;
            W4Tl[tt] = (u16)lo;
        }
    } else {
        // ---- k_count: CSR counts + z histogram ----
        int e = (b - 960) * 256 + t;
        if (e < NE) atomicAdd(&counts[eidx[NE + e]], 1);
        if (e < NN) {
            const float* row = na + (size_t)e * 10;
            int z = 0;
            #pragma unroll
            for (int w = 1; w < 10; ++w) if (row[w] > 0.5f) z = w;
            atomicAdd(&zcnt[z], 1);
        }
    }
}

__global__ __launch_bounds__(1024) void k_scan(int* __restrict__ counts,
                                               int* __restrict__ row_start,
                                               const int* __restrict__ zcnt,
                                               int* __restrict__ zrs, int* __restrict__ zcur) {
    __shared__ int sd[1024];
    int t = threadIdx.x;
    int c[8];
    int s = 0;
    #pragma unroll
    for (int i = 0; i < 8; ++i) { c[i] = counts[t * 8 + i]; s += c[i]; }
    sd[t] = s;
    __syncthreads();
    for (int off = 1; off < 1024; off <<= 1) {
        int v = (t >= off) ? sd[t - off] : 0;
        __syncthreads();
        sd[t] += v;
        __syncthreads();
    }
    int run = (t == 0) ? 0 : sd[t - 1];
    #pragma unroll
    for (int i = 0; i < 8; ++i) {
        row_start[t * 8 + i] = run;
        counts[t * 8 + i] = run;   // cursor
        run += c[i];
    }
    if (t == 1023) row_start[8192] = run;
    if (t == 0) {
        int zr = 0;
        for (int i = 0; i < 10; ++i) { zrs[i] = zr; zcur[i] = zr; zr += zcnt[i]; }
        zrs[10] = zr;
    }
}

__global__ void k_scatter(const int* __restrict__ eidx, const float* __restrict__ na,
                          int* __restrict__ cursor, int* __restrict__ elist,
                          int* __restrict__ zcur, int* __restrict__ znodes) {
    int e = blockIdx.x * 256 + threadIdx.x;
    if (e < NE) {
        int p = atomicAdd(&cursor[eidx[NE + e]], 1);
        elist[p] = e;
    }
    if (e < NN) {
        const float* row = na + (size_t)e * 10;
        int z = 0;
        #pragma unroll
        for (int w = 1; w < 10; ++w) if (row[w] > 0.5f) z = w;
        int p = atomicAdd(&zcur[z], 1);
        znodes[p] = e;
    }
}

// ---------------- canonicalize elist: per-node ascending sort (determinism) ----------------
__global__ __launch_bounds__(256) void k_sort(const int* __restrict__ row_start,
                                              int* __restrict__ elist) {
    __shared__ int buf[SCAP];
    int n0 = blockIdx.x * 256;
    int t = threadIdx.x;
    int r0 = row_start[n0], r1 = row_start[n0 + 256];
    int len = r1 - r0;
    if (len <= SCAP) {
        for (int i = t; i < len; i += 256) buf[i] = elist[r0 + i];
        __syncthreads();
        int a0 = row_start[n0 + t] - r0, a1 = row_start[n0 + t + 1] - r0;
        for (int i = a0 + 1; i < a1; ++i) {
            int key = buf[i]; int j = i - 1;
            while (j >= a0 && buf[j] > key) { buf[j + 1] = buf[j]; --j; }
            buf[j + 1] = key;
        }
        __syncthreads();
        for (int i = t; i < len; i += 256) elist[r0 + i] = buf[i];
    } else {
        int a0 = row_start[n0 + t], a1 = row_start[n0 + t + 1];
        for (int i = a0 + 1; i < a1; ++i) {
            int key = elist[i]; int j = i - 1;
            while (j >= a0 && elist[j] > key) { elist[j + 1] = elist[j]; --j; }
            elist[j + 1] = key;
        }
    }
}

// ---------------- BARRIER-FREE edge kernel: one wave owns 16 edges end-to-end ----------------
__global__ __launch_bounds__(256, 4) void k_edgew(const float* __restrict__ ef,
                                                  const int* __restrict__ eidx,
                                                  const int* __restrict__ elist,
                                                  const float* __restrict__ b1, const float* __restrict__ b2,
                                                  const float* __restrict__ b3, const float* __restrict__ b4,
                                                  const float* __restrict__ W1T, const float* __restrict__ W2T,
                                                  const float* __restrict__ W3T,
                                                  const u16* __restrict__ W4Th, const u16* __restrict__ W4Tl,
                                                  const float* __restrict__ x,
                                                  float* __restrict__ A) {
    __shared__ float ha_s[4][16 * 68];
    __shared__ float hb_s[4][1156];
    __shared__ float ef_s[4][16][8];
    __shared__ int   eid_s[4][16];
    __shared__ int   src_s[4][16];

    int t = threadIdx.x;
    int wv = t >> 6, lane = t & 63;
    int p0 = blockIdx.x * EPB + wv * 16;

    if (lane < 16) {
        int eid = elist[p0 + lane];
        eid_s[wv][lane] = eid;
        src_s[wv][lane] = eidx[eid];
    }
    {
        int i1 = lane;
        int e = i1 >> 3, d = i1 & 7;
        ef_s[wv][e][d] = ef[(size_t)eid_s[wv][e] * 8 + d];
        int i2 = lane + 64;
        e = i2 >> 3; d = i2 & 7;
        ef_s[wv][e][d] = ef[(size_t)eid_s[wv][e] * 8 + d];
    }
    int col = lane;
    float* ha = &ha_s[wv][0];
    float* hb = &hb_s[wv][0];
    {
        float4 w1a = *(const float4*)(W1T + col * 8);
        float4 w1b = *(const float4*)(W1T + col * 8 + 4);
        float bb = b1[col];
        #pragma unroll
        for (int e = 0; e < 16; ++e) {
            const float4* efp = (const float4*)&ef_s[wv][e][0];
            float4 f0 = efp[0], f1 = efp[1];
            float s = bb + f0.x * w1a.x + f0.y * w1a.y + f0.z * w1a.z + f0.w * w1a.w
                        + f1.x * w1b.x + f1.y * w1b.y + f1.z * w1b.z + f1.w * w1b.w;
            ha[e * 68 + col] = silu_f(s);
        }
    }
    {
        float acc[16];
        float bb = b2[col];
        #pragma unroll
        for (int e = 0; e < 16; ++e) acc[e] = bb;
        #pragma unroll
        for (int i = 0; i < 16; ++i) {
            float4 w = *(const float4*)(W2T + col * 64 + i * 4);
            #pragma unroll
            for (int e = 0; e < 16; ++e) {
                float4 h4 = *(const float4*)&ha[e * 68 + i * 4];
                acc[e] += h4.x * w.x + h4.y * w.y + h4.z * w.z + h4.w * w.w;
            }
        }
        #pragma unroll
        for (int e = 0; e < 16; ++e) hb[e * 68 + col] = silu_f(acc[e]);
    }
    {
        float acc[16];
        float bb = b3[col];
        #pragma unroll
        for (int e = 0; e < 16; ++e) acc[e] = bb;
        #pragma unroll
        for (int i = 0; i < 16; ++i) {
            float4 w = *(const float4*)(W3T + col * 64 + i * 4);
            #pragma unroll
            for (int e = 0; e < 16; ++e) {
                float4 h4 = *(const float4*)&hb[e * 68 + i * 4];
                acc[e] += h4.x * w.x + h4.y * w.y + h4.z * w.z + h4.w * w.w;
            }
        }
        #pragma unroll
        for (int e = 0; e < 16; ++e) ha[e * 68 + col] = silu_f(acc[e]);
    }
    u16* HFh = (u16*)hb;
    u16* HFl = ((u16*)hb) + 1152;
    {
        int e = lane >> 2, k0 = (lane & 3) * 16;
        const float* hp = &ha[e * 68 + k0];
        u16x8 vh0, vl0, vh1, vl1;
        #pragma unroll
        for (int r = 0; r < 8; ++r) {
            float v = hp[r];
            unsigned h = bf16_rne(v);
            float fh = __uint_as_float(h << 16);
            unsigned lo = bf16_rne(v - fh);
            vh0[r] = (u16)h; vl0[r] = (u16)lo;
        }
        #pragma unroll
        for (int r = 0; r < 8; ++r) {
            float v = hp[8 + r];
            unsigned h = bf16_rne(v);
            float fh = __uint_as_float(h << 16);
            unsigned lo = bf16_rne(v - fh);
            vh1[r] = (u16)h; vl1[r] = (u16)lo;
        }
        *(u16x8*)&HFh[e * 72 + k0]     = vh0;
        *(u16x8*)&HFh[e * 72 + k0 + 8] = vh1;
        *(u16x8*)&HFl[e * 72 + k0]     = vl0;
        *(u16x8*)&HFl[e * 72 + k0 + 8] = vl1;
    }
    int eloc = lane & 15, kq = lane >> 4;
    const u16* hfh = &HFh[eloc * 72 + kq * 8];
    const u16* hfl = &HFl[eloc * 72 + kq * 8];
    bf16x8 bH0 = *(const bf16x8*)hfh;
    bf16x8 bH1 = *(const bf16x8*)(hfh + 32);
    bf16x8 bL0 = *(const bf16x8*)hfl;
    bf16x8 bL1 = *(const bf16x8*)(hfl + 32);
    const float* xrow = x + (size_t)src_s[wv][eloc] * 128;
    float* arow = A + (size_t)(p0 + eloc) * 512;
    #pragma unroll 4
    for (int mt = 0; mt < 32; ++mt) {
        int m0 = mt * 16;
        const u16* ap  = W4Th + (m0 + eloc) * 64 + kq * 8;
        const u16* apl = W4Tl + (m0 + eloc) * 64 + kq * 8;
        bf16x8 aH0 = *(const bf16x8*)ap;
        bf16x8 aH1 = *(const bf16x8*)(ap + 32);
        bf16x8 aL0 = *(const bf16x8*)apl;
        bf16x8 aL1 = *(const bf16x8*)(apl + 32);
        f32x4 a4 = (f32x4){0.f, 0.f, 0.f, 0.f};
        a4 = __builtin_amdgcn_mfma_f32_16x16x32_bf16(aH0, bH0, a4, 0, 0, 0);
        a4 = __builtin_amdgcn_mfma_f32_16x16x32_bf16(aH1, bH1, a4, 0, 0, 0);
        a4 = __builtin_amdgcn_mfma_f32_16x16x32_bf16(aH0, bL0, a4, 0, 0, 0);
        a4 = __builtin_amdgcn_mfma_f32_16x16x32_bf16(aH1, bL1, a4, 0, 0, 0);
        a4 = __builtin_amdgcn_mfma_f32_16x16x32_bf16(aL0, bH0, a4, 0, 0, 0);
        a4 = __builtin_amdgcn_mfma_f32_16x16x32_bf16(aL1, bH1, a4, 0, 0, 0);
        int c0 = m0 + kq * 4;                 // D row = kq*4 + reg (verified R5-R12)
        float4 b4v4 = *(const float4*)(b4 + c0);
        float4 xv = *(const float4*)(xrow + (c0 & 127));
        float4 o;
        o.x = (a4[0] + b4v4.x) * xv.x;
        o.y = (a4[1] + b4v4.y) * xv.y;
        o.z = (a4[2] + b4v4.z) * xv.z;
        o.w = (a4[3] + b4v4.w) * xv.w;
        *(float4*)(arow + c0) = o;
    }
}

// ---------------- gather + contraction: 3 same-z nodes; linear A streams; C amortized x3 ----------------
__global__ __launch_bounds__(256) void k_gather3(const float* __restrict__ A,
                                                 const float* __restrict__ ea,
                                                 const float* __restrict__ C,
                                                 const int* __restrict__ row_start,
                                                 const int* __restrict__ elist,
                                                 const int* __restrict__ zrs,
                                                 const int* __restrict__ znodes,
                                                 float* __restrict__ out) {
    int z = blockIdx.x / NT3;
    int tile = blockIdx.x % NT3;
    int base = zrs[z], cz = zrs[z + 1] - base;
    int p0 = tile * 3;
    if (p0 >= cz) return;

    __shared__ float msgs_s[3][128 * 20];   // 30.7 KB
    __shared__ float Ys[GCAP3][16];         // 8 KB
    __shared__ int el_s[GCAP3];
    __shared__ int off_s[4];
    __shared__ int rb_s[3];
    __shared__ int nid_s[3];

    int t = threadIdx.x;
    if (t < 3) {
        int nid = (p0 + t < cz) ? znodes[base + p0 + t] : -1;
        nid_s[t] = nid;
        rb_s[t] = (nid >= 0) ? row_start[nid] : 0;
    }
    __syncthreads();
    if (t == 0) {
        int run = 0;
        for (int j = 0; j < 3; ++j) {
            off_s[j] = run;
            int nid = nid_s[j];
            int cnt = (nid >= 0) ? (row_start[nid + 1] - rb_s[j]) : 0;
            run += cnt;
            if (run > GCAP3) run = GCAP3;
        }
        off_s[3] = run;
    }
    __syncthreads();
    for (int j = 0; j < 3; ++j) {
        int a0 = off_s[j], a1 = off_s[j + 1];
        for (int i = a0 + t; i < a1; i += 256) el_s[i] = elist[rb_s[j] + (i - a0)];
    }
    __syncthreads();
    {
        int kk = off_s[3];
        for (int idx = t; idx < kk * 16; idx += 256) {
            int i = idx >> 4, d = idx & 15;
            Ys[i][d] = ea[(size_t)el_s[i] * 16 + d];
        }
    }
    __syncthreads();

    int mc = t & 127, hi = t >> 7;
    // ---- phase 1: per-node segment-sum; A rows contiguous (elist-position order) ----
    for (int j = 0; j < 3; ++j) {
        float acc[8];
        #pragma unroll
        for (int q = 0; q < 8; ++q) acc[q] = 0.f;
        int a0 = off_s[j], a1 = off_s[j + 1];
        const float* Ab = A + (size_t)rb_s[j] * 512;
        #pragma unroll 2
        for (int p = a0; p < a1; ++p) {
            const float* Ae = Ab + (size_t)(p - a0) * 512;
            const float* Yp = &Ys[p][hi * 8];
            float y[8];
            #pragma unroll
            for (int q = 0; q < 8; ++q) y[q] = Yp[q];
            if (hi == 0) {
                float a0v = Ae[mc], a1v = Ae[128 + mc], a2v = Ae[256 + mc];
                acc[0] += a0v * y[0];
                acc[1] += a1v * y[1]; acc[2] += a1v * y[2]; acc[3] += a1v * y[3];
                acc[4] += a2v * y[4]; acc[5] += a2v * y[5]; acc[6] += a2v * y[6]; acc[7] += a2v * y[7];
            } else {
                float a2v = Ae[256 + mc], a3v = Ae[384 + mc];
                acc[0] += a2v * y[0];
                #pragma unroll
                for (int q = 1; q < 8; ++q) acc[q] += a3v * y[q];
            }
        }
        float* mrow = &msgs_s[j][mc * 20 + hi * 8];
        #pragma unroll
        for (int q = 0; q < 8; ++q) mrow[q] = acc[q];
    }
    __syncthreads();

    // ---- phase 2: contraction, C loads amortized over 3 nodes ----
    float o[3][8];
    #pragma unroll
    for (int j = 0; j < 3; ++j)
        #pragma unroll
        for (int q = 0; q < 8; ++q) o[j][q] = 0.f;
    if (hi == 0) {
        const float* C0 = C + (size_t)(0 * 10 + z) * 16384 + mc;
        const float* C1 = C + (size_t)(1 * 10 + z) * 16384 + mc;
        const float* C2 = C + (size_t)(2 * 10 + z) * 16384 + mc;
        #pragma unroll 4
        for (int u = 0; u < 128; ++u) {
            float c0 = C0[u * 128], c1 = C1[u * 128], c2 = C2[u * 128];
            #pragma unroll
            for (int j = 0; j < 3; ++j) {
                const float4* mp = (const float4*)&msgs_s[j][u * 20];
                float4 m0 = mp[0], m1 = mp[1];
                o[j][0] += m0.x * c0;
                o[j][1] += m0.y * c1; o[j][2] += m0.z * c1; o[j][3] += m0.w * c1;
                o[j][4] += m1.x * c2; o[j][5] += m1.y * c2; o[j][6] += m1.z * c2; o[j][7] += m1.w * c2;
            }
        }
    } else {
        const float* C2 = C + (size_t)(2 * 10 + z) * 16384 + mc;
        const float* C3 = C + (size_t)(3 * 10 + z) * 16384 + mc;
        #pragma unroll 4
        for (int u = 0; u < 128; ++u) {
            float c2 = C2[u * 128], c3 = C3[u * 128];
            #pragma unroll
            for (int j = 0; j < 3; ++j) {
                const float4* mp = (const float4*)&msgs_s[j][u * 20 + 8];
                float4 m0 = mp[0], m1 = mp[1];
                o[j][0] += m0.x * c2;
                o[j][1] += m0.y * c3; o[j][2] += m0.z * c3; o[j][3] += m0.w * c3;
                o[j][4] += m1.x * c3; o[j][5] += m1.y * c3; o[j][6] += m1.z * c3; o[j][7] += m1.w * c3;
            }
        }
    }
    #pragma unroll
    for (int j = 0; j < 3; ++j) {
        int nid = nid_s[j];
        if (nid < 0) continue;
        float4 v0 = make_float4(o[j][0], o[j][1], o[j][2], o[j][3]);
        float4 v1 = make_float4(o[j][4], o[j][5], o[j][6], o[j][7]);
        float4* dst = (float4*)(out + (size_t)nid * 2048 + mc * 16 + hi * 8);
        dst[0] = v0;
        dst[1] = v1;
    }
}

extern "C" void kernel_launch(void* const* d_in, const int* in_sizes, int n_in,
                              void* d_out, int out_size, void* d_ws, size_t ws_size,
                              hipStream_t stream) {
    const float* na   = (const float*)d_in[0];
    const float* nf   = (const float*)d_in[1];
    const float* ea   = (const float*)d_in[2];
    const float* ef   = (const float*)d_in[3];
    const int*   eidx = (const int*)d_in[4];
    const float* Wup  = (const float*)d_in[5];
    const float* W1   = (const float*)d_in[6];
    const float* b1   = (const float*)d_in[7];
    const float* W2   = (const float*)d_in[8];
    const float* b2   = (const float*)d_in[9];
    const float* W3   = (const float*)d_in[10];
    const float* b3   = (const float*)d_in[11];
    const float* W4   = (const float*)d_in[12];
    const float* b4   = (const float*)d_in[13];
    const float* Wlin = (const float*)d_in[14];
    const float* Wskip= (const float*)d_in[15];
    float* out = (float*)d_out;

    char* ws = (char*)d_ws;
    float* A        = (float*)(ws + WS_A);
    float* x        = (float*)(ws + WS_X);
    float* C        = (float*)(ws + WS_C);
    int*   counts   = (int*)(ws + WS_COUNTS);
    int*   zcnt     = (int*)(ws + WS_ZCNT);
    int*   rowstart = (int*)(ws + WS_ROWSTART);
    int*   zrs      = (int*)(ws + WS_ZRS);
    int*   zcur     = (int*)(ws + WS_ZCUR);
    int*   elist    = (int*)(ws + WS_ELIST);
    int*   znodes   = (int*)(ws + WS_ZNODES);

    // d_out scratch: prep weights (k_front -> k_edgew); fully overwritten by k_gather3
    float* W1T  = (float*)d_out;
    float* W2T  = W1T + 512;
    float* W3T  = W1T + 4608;
    u16*   W4Th = (u16*)((char*)d_out + 34816);
    u16*   W4Tl = (u16*)((char*)d_out + 100352);

    hipMemsetAsync(counts, 0, 32768 + 64, stream);  // counts + zcnt
    k_front<<<1216, 256, 0, stream>>>(nf, Wup, x, Wlin, Wskip, C,
                                      W1, W2, W3, W4, W1T, W2T, W3T, W4Th, W4Tl,
                                      eidx, na, counts, zcnt);
    k_scan<<<1, 1024, 0, stream>>>(counts, rowstart, zcnt, zrs, zcur);
    k_scatter<<<NE / 256, 256, 0, stream>>>(eidx, na, counts, elist, zcur, znodes);
    k_sort<<<NN / 256, 256, 0, stream>>>(rowstart, elist);
    k_edgew<<<NE / EPB, 256, 0, stream>>>(ef, eidx, elist, b1, b2, b3, b4,
                                          W1T, W2T, W3T, W4Th, W4Tl, x, A);
    k_gather3<<<10 * NT3, 256, 0, stream>>>(A, ea, C, rowstart, elist, zrs, znodes, out);
}